// Round 2
// baseline (703.036 us; speedup 1.0000x reference)
//
#include <hip/hip_runtime.h>

namespace {

constexpr int TT = 1024;   // timesteps
constexpr int NB = 4096;   // batch
constexpr int H0 = 15, H1 = 10, H2 = 2;

// Pre-scales so activations use v_exp_f32 (exp2) directly:
// sigmoid(v) = 1/(1+exp2(-v*L2E)); tanh(u) = 2/(1+exp2(-u*2*L2E)) - 1.
constexpr float L2E  = 1.44269504088896340736f;
constexpr float L2E2 = 2.88539008177792681472f;

typedef float v2f __attribute__((ext_vector_type(2)));
typedef float v4f __attribute__((ext_vector_type(4)));

__device__ __forceinline__ float frcp(float v)  { return __builtin_amdgcn_rcpf(v); }
__device__ __forceinline__ float fexp2(float v) { return __builtin_amdgcn_exp2f(v); }
__device__ __forceinline__ float sigm_p(float v) { return frcp(1.0f + fexp2(-v)); }
__device__ __forceinline__ float tanh_p(float u) {
  return __builtin_fmaf(2.0f, frcp(1.0f + fexp2(-u)), -1.0f);
}

// Guaranteed packed FMA: d = a*b + c on both halves (v_pk_fma_f32).
__device__ __forceinline__ v2f pk_fma(v2f a, v2f b, v2f c) {
  v2f d;
  asm("v_pk_fma_f32 %0, %1, %2, %3" : "=v"(d) : "v"(a), "v"(b), "v"(c));
  return d;
}

}  // namespace

// ===== Split-unit layout: ONE sample per 64-lane wave, 4096 blocks =========
// Lane pair (u, u+32) owns one GRU unit: lane u (side A) computes the
// INPUT-half dots (w_ih . input), lane u+32 (side B) the HIDDEN-half dots
// (w_hh . h). Halves are combined with 3x shfl_xor(32). This halves the
// per-sample VALU issue (max half-span 15 floats -> 8 pk_fma x 3 gates) and
// doubles occupancy (4096 blocks -> 4 waves/SIMD at VGPR<=128), covering the
// ~400-cycle LDS->dot->exp2/rcp dependence chain that limited the 2-wave
// version to 61% VALUBusy.
//
// Per-sample staging (floats): x[0..4] pad[5..7] h0[8..22] pad[23]
// h1[24..33] pad[34..35] h2[36..37] pad[38..47]; dump slots [64..95] absorb
// side-B publishes so the store stays exec-uniform. Windows (16 floats,
// 16B-aligned): A: L0->0, L1->8, L2->24; B: L0->8, L1->24, L2->32.
// Layers skewed (iter i: L0(i), L1(i-1), L2(i-2)) -> one publish/iteration.
// Single-wave block: wave-lockstep + in-order DS pipe; wave_barrier pins
// compiler ordering.
//
// x prefetch: 2 loads in flight (xldA/xldB via manual unroll-2), consumed 2
// iterations after issue -> HBM latency never exposed.
extern "C" __global__ __launch_bounds__(64, 4) void gru3_fused(
    const float* __restrict__ x,
    const float* __restrict__ w_ih0, const float* __restrict__ w_hh0,
    const float* __restrict__ b_ih0, const float* __restrict__ b_hh0,
    const float* __restrict__ w_ih1, const float* __restrict__ w_hh1,
    const float* __restrict__ b_ih1, const float* __restrict__ b_hh1,
    const float* __restrict__ w_ih2, const float* __restrict__ w_hh2,
    const float* __restrict__ b_ih2, const float* __restrict__ b_hh2,
    float* __restrict__ out) {
  __shared__ __attribute__((aligned(16))) float stage[112];

  const int lane = threadIdx.x;       // one sample per wave
  const int side = lane >> 5;         // 0 = input-half (A), 1 = hidden-half (B)
  const int l32  = lane & 31;
  const int b    = blockIdx.x;

  int cls, u;
  if (l32 < 15)      { cls = 0; u = l32; }
  else if (l32 < 25) { cls = 1; u = l32 - 15; }
  else if (l32 < 27) { cls = 2; u = l32 - 25; }
  else               { cls = 3; u = l32 - 27; }   // x-loader

  const bool isA  = (side == 0);
  const bool is_x = (cls == 3);
  const bool is_o = (isA && cls == 2);
  const int  istart = is_x ? 3 : cls;   // suppress h-update pre-first-step
  const int  xj   = is_x ? u : 0;       // in-bounds x column for everyone

  // window start (floats) and publish slot
  int woff;
  if (is_x)      woff = 0;
  else if (isA)  woff = (cls == 0) ? 0 : (cls == 1) ? 8 : 24;
  else           woff = (cls == 0) ? 8 : (cls == 1) ? 24 : 32;
  const int wpos = isA ? ((cls == 0) ? 8 + u : (cls == 1) ? 24 + u
                        : (cls == 2) ? 36 + u : u)
                       : 64 + l32;      // side B dumps (keeps store uniform)

  // ---- per-lane padded half-weights (zero outside this half's span) ----
  float Wr[16], Wz[16], Wn[16];
#pragma unroll
  for (int j = 0; j < 16; ++j) { Wr[j] = 0.f; Wz[j] = 0.f; Wn[j] = 0.f; }
  float br = 0.f, bz = 0.f, bn = 0.f;

  if (cls == 0) {
    if (isA) {                       // input = x[5] at window floats 0..4
#pragma unroll
      for (int j = 0; j < 5; ++j) {
        Wr[j] = w_ih0[(u         ) * 5 + j] * L2E;
        Wz[j] = w_ih0[(H0 + u    ) * 5 + j] * L2E;
        Wn[j] = w_ih0[(2 * H0 + u) * 5 + j] * L2E2;
      }
      br = (b_ih0[u] + b_hh0[u]) * L2E;
      bz = (b_ih0[H0 + u] + b_hh0[H0 + u]) * L2E;
      bn = b_ih0[2 * H0 + u] * L2E2;
    } else {                         // hidden = h0[15] at window floats 0..14
#pragma unroll
      for (int k = 0; k < 15; ++k) {
        Wr[k] = w_hh0[(u         ) * 15 + k] * L2E;
        Wz[k] = w_hh0[(H0 + u    ) * 15 + k] * L2E;
        Wn[k] = w_hh0[(2 * H0 + u) * 15 + k] * L2E2;
      }
      bn = b_hh0[2 * H0 + u] * L2E2;
    }
  } else if (cls == 1) {
    if (isA) {                       // input = h0[15] at window floats 0..14
#pragma unroll
      for (int k = 0; k < 15; ++k) {
        Wr[k] = w_ih1[(u         ) * 15 + k] * L2E;
        Wz[k] = w_ih1[(H1 + u    ) * 15 + k] * L2E;
        Wn[k] = w_ih1[(2 * H1 + u) * 15 + k] * L2E2;
      }
      br = (b_ih1[u] + b_hh1[u]) * L2E;
      bz = (b_ih1[H1 + u] + b_hh1[H1 + u]) * L2E;
      bn = b_ih1[2 * H1 + u] * L2E2;
    } else {                         // hidden = h1[10] at window floats 0..9
#pragma unroll
      for (int k = 0; k < 10; ++k) {
        Wr[k] = w_hh1[(u         ) * 10 + k] * L2E;
        Wz[k] = w_hh1[(H1 + u    ) * 10 + k] * L2E;
        Wn[k] = w_hh1[(2 * H1 + u) * 10 + k] * L2E2;
      }
      bn = b_hh1[2 * H1 + u] * L2E2;
    }
  } else if (cls == 2) {
    if (isA) {                       // input = h1[10] at window floats 0..9
#pragma unroll
      for (int k = 0; k < 10; ++k) {
        Wr[k] = w_ih2[(u         ) * 10 + k] * L2E;
        Wz[k] = w_ih2[(H2 + u    ) * 10 + k] * L2E;
        Wn[k] = w_ih2[(2 * H2 + u) * 10 + k] * L2E2;
      }
      br = (b_ih2[u] + b_hh2[u]) * L2E;
      bz = (b_ih2[H2 + u] + b_hh2[H2 + u]) * L2E;
      bn = b_ih2[2 * H2 + u] * L2E2;
    } else {                         // hidden = h2[2] at window floats 4..5
#pragma unroll
      for (int k = 0; k < 2; ++k) {
        Wr[4 + k] = w_hh2[(u         ) * 2 + k] * L2E;
        Wz[4 + k] = w_hh2[(H2 + u    ) * 2 + k] * L2E;
        Wn[4 + k] = w_hh2[(2 * H2 + u) * 2 + k] * L2E2;
      }
      bn = b_hh2[2 * H2 + u] * L2E2;
    }
  }

  // pack to float2 for v_pk_fma_f32
  v2f WR[8], WZ[8], WN[8];
#pragma unroll
  for (int j = 0; j < 8; ++j) {
    WR[j] = (v2f){Wr[2 * j], Wr[2 * j + 1]};
    WZ[j] = (v2f){Wz[2 * j], Wz[2 * j + 1]};
    WN[j] = (v2f){Wn[2 * j], Wn[2 * j + 1]};
  }

  // ---- init staging (zeros = h(-1) states + pads), publish x(0) ----
  for (int j = lane; j < 112; j += 64) stage[j] = 0.0f;

  // x pipeline: at top of iter i, xw=x(i+1), xn=x(i+2), xm=x(i+3);
  // xldA/xldB = in-flight loads of x(i+4), x(i+5) (consumed 2 iters later).
  float xw, xn, xm, xldA, xldB;
  const size_t xstep = (size_t)NB * 5;
  {
    const size_t base = (size_t)b * 5 + xj;
    const float x0 = x[base];                 // t=0
    xw   = x[1 * xstep + base];
    xn   = x[2 * xstep + base];
    xm   = x[3 * xstep + base];
    xldA = x[4 * xstep + base];               // consumed at iter 0
    xldB = x[5 * xstep + base];               // consumed at iter 1
    if (is_x && isA) stage[u] = x0;
  }
  __builtin_amdgcn_wave_barrier();

  float h = 0.0f;
  const v4f* wloc = (const v4f*)&stage[woff];
  float* pub = &stage[wpos];

  const float* xp = x + (size_t)6 * xstep + (size_t)b * 5 + xj;
  float* op = out + (size_t)b * H2 + (is_o ? u : 0);  // t = i-2 target
  const size_t ostep = (size_t)NB * H2;

#define GRU_DOT2(J, QH)              \
    aR = pk_fma(WR[J], (QH), aR);    \
    aZ = pk_fma(WZ[J], (QH), aZ);    \
    aN = pk_fma(WN[J], (QH), aN);

// One skewed-pipeline half-unit GRU step. XR = in-flight x-load register
// consumed this iteration (issued 2 iterations ago), re-issued for row
// min(I+6, TT-1).
#define GRU_BODY(I, XR)                                                   \
  {                                                                       \
    const v4f q0 = wloc[0], q1 = wloc[1], q2 = wloc[2], q3 = wloc[3];     \
    v2f aR = (v2f){br, 0.f};                                              \
    v2f aZ = (v2f){bz, 0.f};                                              \
    v2f aN = (v2f){bn, 0.f};                                              \
    GRU_DOT2(0, q0.lo)                                                    \
    GRU_DOT2(1, q0.hi)                                                    \
    GRU_DOT2(2, q1.lo)                                                    \
    GRU_DOT2(3, q1.hi)                                                    \
    GRU_DOT2(4, q2.lo)                                                    \
    GRU_DOT2(5, q2.hi)                                                    \
    GRU_DOT2(6, q3.lo)                                                    \
    GRU_DOT2(7, q3.hi)                                                    \
    const float sR = aR.x + aR.y;                                         \
    const float sZ = aZ.x + aZ.y;                                         \
    const float sN = aN.x + aN.y;                                         \
    const float oR = __shfl_xor(sR, 32);                                  \
    const float oZ = __shfl_xor(sZ, 32);                                  \
    const float oN = __shfl_xor(sN, 32);                                  \
    const float r  = sigm_p(sR + oR);                                     \
    const float z  = sigm_p(sZ + oZ);                                     \
    const float nx = isA ? sN : oN;   /* input-half n-preact (has b_ih) */ \
    const float nh = isA ? oN : sN;   /* hidden-half n-preact (has b_hh) */\
    const float n  = tanh_p(nx + r * nh);                                 \
    const float hnew = n + z * (h - n);                                   \
    h = ((I) >= istart) ? hnew : h;                                       \
    *pub = is_x ? xw : h;            /* units: h; loaders: x(I+1); B: dump */\
    if ((I) >= 2) {                  /* uniform branch */                  \
      if (is_o) *op = h;             /* t = I-2, exec-masked */            \
      op += ostep;                                                        \
    }                                                                     \
    xw = xn; xn = xm; xm = XR;       /* waits on 2-iter-old load only */   \
    XR = *xp;                        /* issue x(min(I+6,TT-1)), no wait */ \
    if ((I) + 7 < TT) xp += xstep;   /* uniform scalar condition */        \
    __builtin_amdgcn_wave_barrier(); /* next reads after publishes */      \
  }

  // 1026 iterations (even) -> 513 unroll-2 pairs; xldA/xldB alternate so the
  // two in-flight loads live in statically distinct registers.
#pragma unroll 1
  for (int i = 0; i <= TT + 1; i += 2) {
    GRU_BODY(i,     xldA)
    GRU_BODY(i + 1, xldB)
  }

#undef GRU_BODY
#undef GRU_DOT2
}

extern "C" void kernel_launch(void* const* d_in, const int* in_sizes, int n_in,
                              void* d_out, int out_size, void* d_ws, size_t ws_size,
                              hipStream_t stream) {
  (void)in_sizes; (void)n_in; (void)d_ws; (void)ws_size; (void)out_size;
  const float* x     = (const float*)d_in[0];
  const float* w_ih0 = (const float*)d_in[1];
  const float* w_hh0 = (const float*)d_in[2];
  const float* b_ih0 = (const float*)d_in[3];
  const float* b_hh0 = (const float*)d_in[4];
  const float* w_ih1 = (const float*)d_in[5];
  const float* w_hh1 = (const float*)d_in[6];
  const float* b_ih1 = (const float*)d_in[7];
  const float* b_hh1 = (const float*)d_in[8];
  const float* w_ih2 = (const float*)d_in[9];
  const float* w_hh2 = (const float*)d_in[10];
  const float* b_ih2 = (const float*)d_in[11];
  const float* b_hh2 = (const float*)d_in[12];
  float* out = (float*)d_out;

  gru3_fused<<<NB, 64, 0, stream>>>(
      x, w_ih0, w_hh0, b_ih0, b_hh0,
      w_ih1, w_hh1, b_ih1, b_hh1,
      w_ih2, w_hh2, b_ih2, b_hh2, out);
}

// Round 3
// 616.173 us; speedup vs baseline: 1.1410x; 1.1410x over previous
//
#include <hip/hip_runtime.h>

namespace {

constexpr int TT = 1024;   // timesteps
constexpr int NB = 4096;   // batch
constexpr int H0 = 15, H1 = 10, H2 = 2;

// Pre-scales so activations use v_exp_f32 (exp2) directly:
// sigmoid(v) = 1/(1+exp2(-v*L2E)); tanh(u) = 2/(1+exp2(-u*2*L2E)) - 1.
constexpr float L2E  = 1.44269504088896340736f;
constexpr float L2E2 = 2.88539008177792681472f;

// Staging vector per sample (floats): x[0..4] pad[5..7] h0[8..22] pad[23]
// h1[24..33] pad[34..35] h2[36..37] pad[38..47].  Window starts (16B-aligned):
// L0 -> 0 (x+h0), L1 -> 8 (h0+h1), L2 -> 24 (h1+h2). Window = 26 floats used.
constexpr int SSTRIDE = 48;

typedef float v2f __attribute__((ext_vector_type(2)));
typedef float v4f __attribute__((ext_vector_type(4)));

__device__ __forceinline__ float frcp(float v)  { return __builtin_amdgcn_rcpf(v); }
__device__ __forceinline__ float fexp2(float v) { return __builtin_amdgcn_exp2f(v); }
__device__ __forceinline__ float sigm_p(float v) { return frcp(1.0f + fexp2(-v)); }
__device__ __forceinline__ float tanh_p(float u) {
  return __builtin_fmaf(2.0f, frcp(1.0f + fexp2(-u)), -1.0f);
}

// Guaranteed packed FMA: d = a*b + c on both halves (v_pk_fma_f32).
__device__ __forceinline__ v2f pk_fma(v2f a, v2f b, v2f c) {
  v2f d;
  asm("v_pk_fma_f32 %0, %1, %2, %3" : "=v"(d) : "v"(a), "v"(b), "v"(c));
  return d;
}

}  // namespace

// Grid: 2048 blocks x 64 threads = 2 waves/SIMD. Wave = 2 samples x 32 lanes.
// Per sample: lanes 0-14 = L0 units, 15-24 = L1 units, 25-26 = L2 units,
// 27-31 = x-loaders. Uniform code: every lane reads a 26-float window of
// [x|h0|h1|h2] staging. Layers skewed (iter i: L0(i), L1(i-1), L2(i-2)) ->
// one publish/iteration. Single-wave block: wave-lockstep + in-order DS pipe;
// wave_barrier pins compiler ordering.
//
// This revision vs the 574us round-1 kernel (layout identical):
//  * Dead-pair trimming: pk_fma is inline asm -> compiler can't fold the
//    zero-padded pairs. Union of nonzero spans across lane classes:
//    R pairs 0-12, Z pairs 0-12, Nx pairs 0-7, Nh pairs 4-12
//    -> 43 pk_fma/iter instead of 56 (-13 instr, ~13% of VALU issue).
//  * Chain split: each gate uses two accumulators (parallel 4-7 deep chains)
//    combined by a 2-level add tree -> halves dot-phase dependence depth.
//  * x prefetch unchanged: 2 loads in flight, consumed 2 iters after issue.
extern "C" __global__ __launch_bounds__(64, 2) void gru3_fused(
    const float* __restrict__ x,
    const float* __restrict__ w_ih0, const float* __restrict__ w_hh0,
    const float* __restrict__ b_ih0, const float* __restrict__ b_hh0,
    const float* __restrict__ w_ih1, const float* __restrict__ w_hh1,
    const float* __restrict__ b_ih1, const float* __restrict__ b_hh1,
    const float* __restrict__ w_ih2, const float* __restrict__ w_hh2,
    const float* __restrict__ b_ih2, const float* __restrict__ b_hh2,
    float* __restrict__ out) {
  // 2 samples * 48 + tail pad so L2's window over-read stays in-buffer.
  __shared__ __attribute__((aligned(16))) float stage[112];

  const int tid  = threadIdx.x;
  const int lane = tid & 31;
  const int smp  = tid >> 5;
  const int b    = blockIdx.x * 2 + smp;
  const int sbase = smp * SSTRIDE;

  int cls, u;
  if (lane < 15)      { cls = 0; u = lane; }
  else if (lane < 25) { cls = 1; u = lane - 15; }
  else if (lane < 27) { cls = 2; u = lane - 25; }
  else                { cls = 3; u = lane - 27; }   // x-loader

  const int  woff   = (cls == 0) ? 0 : (cls == 1) ? 8 : (cls == 2) ? 24 : 0;
  const int  wpos   = (cls == 0) ? 8 + u : (cls == 1) ? 24 + u
                    : (cls == 2) ? 36 + u : u;
  const int  istart = cls;            // suppress h-update until layer's first step
  const bool is_x   = (cls == 3);
  const bool is_o   = (cls == 2);
  const int  xj     = is_x ? u : 0;   // in-bounds x column for everyone

  // ---- per-lane padded weight vectors (zero outside class's inputs) ----
  float Wr[28], Wz[28], Wnx[28], Wnh[28];
#pragma unroll
  for (int j = 0; j < 28; ++j) { Wr[j] = 0.f; Wz[j] = 0.f; Wnx[j] = 0.f; Wnh[j] = 0.f; }
  float br = 0.f, bz = 0.f, bnx = 0.f, bnh = 0.f;

  if (cls == 0) {
#pragma unroll
    for (int j = 0; j < 5; ++j) {
      Wr [j] = w_ih0[(u         ) * 5 + j] * L2E;
      Wz [j] = w_ih0[(H0 + u    ) * 5 + j] * L2E;
      Wnx[j] = w_ih0[(2 * H0 + u) * 5 + j] * L2E2;
    }
#pragma unroll
    for (int k = 0; k < 15; ++k) {
      Wr [8 + k] = w_hh0[(u         ) * 15 + k] * L2E;
      Wz [8 + k] = w_hh0[(H0 + u    ) * 15 + k] * L2E;
      Wnh[8 + k] = w_hh0[(2 * H0 + u) * 15 + k] * L2E2;
    }
    br  = (b_ih0[u] + b_hh0[u]) * L2E;
    bz  = (b_ih0[H0 + u] + b_hh0[H0 + u]) * L2E;
    bnx = b_ih0[2 * H0 + u] * L2E2;
    bnh = b_hh0[2 * H0 + u] * L2E2;
  } else if (cls == 1) {
#pragma unroll
    for (int k = 0; k < 15; ++k) {
      Wr [k] = w_ih1[(u         ) * 15 + k] * L2E;
      Wz [k] = w_ih1[(H1 + u    ) * 15 + k] * L2E;
      Wnx[k] = w_ih1[(2 * H1 + u) * 15 + k] * L2E2;
    }
#pragma unroll
    for (int k = 0; k < 10; ++k) {
      Wr [16 + k] = w_hh1[(u         ) * 10 + k] * L2E;
      Wz [16 + k] = w_hh1[(H1 + u    ) * 10 + k] * L2E;
      Wnh[16 + k] = w_hh1[(2 * H1 + u) * 10 + k] * L2E2;
    }
    br  = (b_ih1[u] + b_hh1[u]) * L2E;
    bz  = (b_ih1[H1 + u] + b_hh1[H1 + u]) * L2E;
    bnx = b_ih1[2 * H1 + u] * L2E2;
    bnh = b_hh1[2 * H1 + u] * L2E2;
  } else if (cls == 2) {
#pragma unroll
    for (int k = 0; k < 10; ++k) {
      Wr [k] = w_ih2[(u         ) * 10 + k] * L2E;
      Wz [k] = w_ih2[(H2 + u    ) * 10 + k] * L2E;
      Wnx[k] = w_ih2[(2 * H2 + u) * 10 + k] * L2E2;
    }
#pragma unroll
    for (int k = 0; k < 2; ++k) {
      Wr [12 + k] = w_hh2[(u         ) * 2 + k] * L2E;
      Wz [12 + k] = w_hh2[(H2 + u    ) * 2 + k] * L2E;
      Wnh[12 + k] = w_hh2[(2 * H2 + u) * 2 + k] * L2E2;
    }
    br  = (b_ih2[u] + b_hh2[u]) * L2E;
    bz  = (b_ih2[H2 + u] + b_hh2[H2 + u]) * L2E;
    bnx = b_ih2[2 * H2 + u] * L2E2;
    bnh = b_hh2[2 * H2 + u] * L2E2;
  }

  // Pack ONLY the pairs that are nonzero for at least one lane class:
  //   R: pairs 0..12   Z: pairs 0..12   Nx: pairs 0..7   Nh: pairs 4..12
  // (pair p covers window floats 2p, 2p+1; all trimmed pairs are zero for
  //  every class, so dropping them is exact.)
  v2f WR2[13], WZ2[13], WNX2[8], WNH2[9];
#pragma unroll
  for (int j = 0; j < 13; ++j) {
    WR2[j] = (v2f){Wr[2 * j], Wr[2 * j + 1]};
    WZ2[j] = (v2f){Wz[2 * j], Wz[2 * j + 1]};
  }
#pragma unroll
  for (int j = 0; j < 8; ++j)  WNX2[j] = (v2f){Wnx[2 * j], Wnx[2 * j + 1]};
#pragma unroll
  for (int j = 0; j < 9; ++j)  WNH2[j] = (v2f){Wnh[2 * (j + 4)], Wnh[2 * (j + 4) + 1]};

  // ---- init staging (zeros = h(-1) states + pads), publish x(0) ----
  for (int j = tid; j < 112; j += 64) stage[j] = 0.0f;

  // x pipeline: at top of iter i, xw=x(i+1), xn=x(i+2), xm=x(i+3);
  // xldA/xldB = in-flight loads of x(i+4), x(i+5) (consumed 2 iters later).
  float xw, xn, xm, xldA, xldB;
  const size_t xstep = (size_t)NB * 5;
  {
    const size_t base = (size_t)b * 5 + xj;
    const float x0 = x[base];                 // t=0
    xw   = x[1 * xstep + base];
    xn   = x[2 * xstep + base];
    xm   = x[3 * xstep + base];
    xldA = x[4 * xstep + base];               // consumed at iter 0
    xldB = x[5 * xstep + base];               // consumed at iter 1
    if (is_x) stage[sbase + u] = x0;
  }
  __builtin_amdgcn_wave_barrier();

  float h = 0.0f;
  const float* wbase = &stage[sbase + woff];
  const v4f* wloc = (const v4f*)wbase;
  float* pub = &stage[sbase + wpos];

  const float* xp = x + (size_t)6 * xstep + (size_t)b * 5 + xj;
  float* op = out + (size_t)b * H2 + (is_o ? u : 0);  // t = i-2 target
  const size_t ostep = (size_t)NB * H2;

// One skewed-pipeline GRU step. XR = in-flight x-load register consumed this
// iteration (issued 2 iterations ago), re-issued for row min(I+6, TT-1).
// Pair->window-half map: P0=q0.lo P1=q0.hi P2=q1.lo P3=q1.hi P4=q2.lo
// P5=q2.hi P6=q3.lo P7=q3.hi P8=q4.lo P9=q4.hi P10=q5.lo P11=q5.hi P12=q6.
#define GRU_BODY(I, XR)                                                   \
  {                                                                       \
    const v4f q0 = wloc[0], q1 = wloc[1], q2 = wloc[2], q3 = wloc[3];     \
    const v4f q4 = wloc[4], q5 = wloc[5];                                 \
    const v2f q6 = ((const v2f*)wbase)[12];                               \
    v2f aR0 = (v2f){br,  0.f}, aR1 = (v2f){0.f, 0.f};                     \
    v2f aZ0 = (v2f){bz,  0.f}, aZ1 = (v2f){0.f, 0.f};                     \
    v2f aX0 = (v2f){bnx, 0.f}, aX1 = (v2f){0.f, 0.f};                     \
    v2f aH0 = (v2f){bnh, 0.f}, aH1 = (v2f){0.f, 0.f};                     \
    /* R: pairs 0..6 -> aR0, 7..12 -> aR1 (7+6) */                        \
    aR0 = pk_fma(WR2[0],  q0.lo, aR0);                                    \
    aR0 = pk_fma(WR2[1],  q0.hi, aR0);                                    \
    aR0 = pk_fma(WR2[2],  q1.lo, aR0);                                    \
    aR0 = pk_fma(WR2[3],  q1.hi, aR0);                                    \
    aR0 = pk_fma(WR2[4],  q2.lo, aR0);                                    \
    aR0 = pk_fma(WR2[5],  q2.hi, aR0);                                    \
    aR0 = pk_fma(WR2[6],  q3.lo, aR0);                                    \
    aR1 = pk_fma(WR2[7],  q3.hi, aR1);                                    \
    aR1 = pk_fma(WR2[8],  q4.lo, aR1);                                    \
    aR1 = pk_fma(WR2[9],  q4.hi, aR1);                                    \
    aR1 = pk_fma(WR2[10], q5.lo, aR1);                                    \
    aR1 = pk_fma(WR2[11], q5.hi, aR1);                                    \
    aR1 = pk_fma(WR2[12], q6,    aR1);                                    \
    /* Z: same split */                                                   \
    aZ0 = pk_fma(WZ2[0],  q0.lo, aZ0);                                    \
    aZ0 = pk_fma(WZ2[1],  q0.hi, aZ0);                                    \
    aZ0 = pk_fma(WZ2[2],  q1.lo, aZ0);                                    \
    aZ0 = pk_fma(WZ2[3],  q1.hi, aZ0);                                    \
    aZ0 = pk_fma(WZ2[4],  q2.lo, aZ0);                                    \
    aZ0 = pk_fma(WZ2[5],  q2.hi, aZ0);                                    \
    aZ0 = pk_fma(WZ2[6],  q3.lo, aZ0);                                    \
    aZ1 = pk_fma(WZ2[7],  q3.hi, aZ1);                                    \
    aZ1 = pk_fma(WZ2[8],  q4.lo, aZ1);                                    \
    aZ1 = pk_fma(WZ2[9],  q4.hi, aZ1);                                    \
    aZ1 = pk_fma(WZ2[10], q5.lo, aZ1);                                    \
    aZ1 = pk_fma(WZ2[11], q5.hi, aZ1);                                    \
    aZ1 = pk_fma(WZ2[12], q6,    aZ1);                                    \
    /* Nx: pairs 0..3 -> aX0, 4..7 -> aX1 */                              \
    aX0 = pk_fma(WNX2[0], q0.lo, aX0);                                    \
    aX0 = pk_fma(WNX2[1], q0.hi, aX0);                                    \
    aX0 = pk_fma(WNX2[2], q1.lo, aX0);                                    \
    aX0 = pk_fma(WNX2[3], q1.hi, aX0);                                    \
    aX1 = pk_fma(WNX2[4], q2.lo, aX1);                                    \
    aX1 = pk_fma(WNX2[5], q2.hi, aX1);                                    \
    aX1 = pk_fma(WNX2[6], q3.lo, aX1);                                    \
    aX1 = pk_fma(WNX2[7], q3.hi, aX1);                                    \
    /* Nh: pairs 4..8 -> aH0, 9..12 -> aH1 (WNH2[j] = pair j+4) */        \
    aH0 = pk_fma(WNH2[0], q2.lo, aH0);                                    \
    aH0 = pk_fma(WNH2[1], q2.hi, aH0);                                    \
    aH0 = pk_fma(WNH2[2], q3.lo, aH0);                                    \
    aH0 = pk_fma(WNH2[3], q3.hi, aH0);                                    \
    aH0 = pk_fma(WNH2[4], q4.lo, aH0);                                    \
    aH1 = pk_fma(WNH2[5], q4.hi, aH1);                                    \
    aH1 = pk_fma(WNH2[6], q5.lo, aH1);                                    \
    aH1 = pk_fma(WNH2[7], q5.hi, aH1);                                    \
    aH1 = pk_fma(WNH2[8], q6,    aH1);                                    \
    /* 2-level horizontal sums (chains halved vs single-acc version) */   \
    const float sR  = (aR0.x + aR0.y) + (aR1.x + aR1.y);                  \
    const float sZ  = (aZ0.x + aZ0.y) + (aZ1.x + aZ1.y);                  \
    const float sNx = (aX0.x + aX0.y) + (aX1.x + aX1.y);                  \
    const float sNh = (aH0.x + aH0.y) + (aH1.x + aH1.y);                  \
    const float r = sigm_p(sR);                                           \
    const float z = sigm_p(sZ);                                           \
    const float n = tanh_p(sNx + r * sNh);                                \
    const float hnew = n + z * (h - n);                                   \
    h = ((I) >= istart) ? hnew : h;  /* junk-suppress pre-first-step */    \
    *pub = is_x ? xw : h;            /* publish h (units) or x(I+1) */     \
    if ((I) >= 2) {                  /* uniform branch */                  \
      if (is_o) *op = h;             /* t = I-2, exec-masked */            \
      op += ostep;                                                        \
    }                                                                     \
    xw = xn; xn = xm; xm = XR;       /* waits on 2-iter-old load only */   \
    XR = *xp;                        /* issue x(min(I+6,TT-1)), no wait */ \
    if ((I) + 7 < TT) xp += xstep;   /* uniform scalar condition */        \
    __builtin_amdgcn_wave_barrier(); /* next reads after publishes */      \
  }

  // 1026 iterations (even) -> 513 unroll-2 pairs; xldA/xldB alternate so the
  // two in-flight loads live in statically distinct registers.
#pragma unroll 1
  for (int i = 0; i <= TT + 1; i += 2) {
    GRU_BODY(i,     xldA)
    GRU_BODY(i + 1, xldB)
  }

#undef GRU_BODY
}

extern "C" void kernel_launch(void* const* d_in, const int* in_sizes, int n_in,
                              void* d_out, int out_size, void* d_ws, size_t ws_size,
                              hipStream_t stream) {
  (void)in_sizes; (void)n_in; (void)d_ws; (void)ws_size; (void)out_size;
  const float* x     = (const float*)d_in[0];
  const float* w_ih0 = (const float*)d_in[1];
  const float* w_hh0 = (const float*)d_in[2];
  const float* b_ih0 = (const float*)d_in[3];
  const float* b_hh0 = (const float*)d_in[4];
  const float* w_ih1 = (const float*)d_in[5];
  const float* w_hh1 = (const float*)d_in[6];
  const float* b_ih1 = (const float*)d_in[7];
  const float* b_hh1 = (const float*)d_in[8];
  const float* w_ih2 = (const float*)d_in[9];
  const float* w_hh2 = (const float*)d_in[10];
  const float* b_ih2 = (const float*)d_in[11];
  const float* b_hh2 = (const float*)d_in[12];
  float* out = (float*)d_out;

  gru3_fused<<<NB / 2, 64, 0, stream>>>(
      x, w_ih0, w_hh0, b_ih0, b_hh0,
      w_ih1, w_hh1, b_ih1, b_hh1,
      w_ih2, w_hh2, b_ih2, b_hh2, out);
}

// Round 4
// 518.702 us; speedup vs baseline: 1.3554x; 1.1879x over previous
//
#include <hip/hip_runtime.h>

namespace {

constexpr int TT = 1024;   // timesteps
constexpr int NB = 4096;   // batch
constexpr int H0 = 15, H1 = 10, H2 = 2;

// Pre-scales so activations use v_exp_f32 (exp2) directly:
// sigmoid(v) = 1/(1+exp2(-v*L2E)); tanh(u) = 2/(1+exp2(-u*2*L2E)) - 1.
constexpr float L2E  = 1.44269504088896340736f;
constexpr float L2E2 = 2.88539008177792681472f;

// Staging vector per sample (floats): x[0..4] pad[5..7] h0[8..22] pad[23]
// h1[24..33] pad[34..35] h2[36..37] pad[38..47].  Window starts (16B-aligned):
// L0 -> 0 (x+h0), L1 -> 8 (h0+h1), L2 -> 24 (h1+h2). Window = 26 floats used.
constexpr int SSTRIDE = 48;

typedef float v2f __attribute__((ext_vector_type(2)));
typedef float v4f __attribute__((ext_vector_type(4)));

__device__ __forceinline__ float frcp(float v)  { return __builtin_amdgcn_rcpf(v); }
__device__ __forceinline__ float fexp2(float v) { return __builtin_amdgcn_exp2f(v); }
__device__ __forceinline__ float sigm_p(float v) { return frcp(1.0f + fexp2(-v)); }
__device__ __forceinline__ float tanh_p(float u) {
  return __builtin_fmaf(2.0f, frcp(1.0f + fexp2(-u)), -1.0f);
}

// Guaranteed packed FMA: d = a*b + c on both halves (v_pk_fma_f32).
__device__ __forceinline__ v2f pk_fma(v2f a, v2f b, v2f c) {
  v2f d;
  asm("v_pk_fma_f32 %0, %1, %2, %3" : "=v"(d) : "v"(a), "v"(b), "v"(c));
  return d;
}

}  // namespace

// Grid: 2048 blocks x 64 threads = 2 waves/SIMD (grid-limited). Wave = 2
// samples x 32 lanes. Per sample: lanes 0-14 = L0 units, 15-24 = L1 units,
// 25-26 = L2 units, 27-31 = x-loaders. Layers skewed (iter i: L0(i), L1(i-1),
// L2(i-2)) -> one publish/iteration. Single-wave block: wave-lockstep +
// in-order DS pipe; wave_barrier pins compiler ordering.
//
// This revision: UNLOCK THE REGISTER BUDGET. Occupancy is grid-capped at 2
// waves/SIMD, so 256 VGPRs/wave are available, but the compiler was choosing
// ~100 and re-phasing the 7 window ds_reads to just-before-use -- exposing
// LDS latency several times per iteration (the ~60% VALUBusy / ~40% stall
// signature). amdgpu_waves_per_eu(2,2) tells it only 2 waves are needed:
// the whole working set (~160 regs: 43 weight pairs, 7 q-vectors, 10 acc
// pairs, bias pairs, 6-deep x pipeline) stays resident, reads hoist to the
// top of the body, latency is paid once.
//   + bias pairs as C of the first pk_fma of each chain (no init movs)
//   + 3-accumulator split for R/Z (max dep chain 5 instead of 7)
//   + 6-deep rotating x registers (no shift movs; 6 loads in flight,
//     consumed 6 iterations after issue)
//   + peeled prologue (I=0..5): steady body has no istart cndmask and
//     stores unconditionally.
extern "C" __global__ __launch_bounds__(64)
__attribute__((amdgpu_waves_per_eu(2, 2)))
void gru3_fused(
    const float* __restrict__ x,
    const float* __restrict__ w_ih0, const float* __restrict__ w_hh0,
    const float* __restrict__ b_ih0, const float* __restrict__ b_hh0,
    const float* __restrict__ w_ih1, const float* __restrict__ w_hh1,
    const float* __restrict__ b_ih1, const float* __restrict__ b_hh1,
    const float* __restrict__ w_ih2, const float* __restrict__ w_hh2,
    const float* __restrict__ b_ih2, const float* __restrict__ b_hh2,
    float* __restrict__ out) {
  // 2 samples * 48 + tail pad so L2's window over-read stays in-buffer.
  __shared__ __attribute__((aligned(16))) float stage[112];

  const int tid  = threadIdx.x;
  const int lane = tid & 31;
  const int smp  = tid >> 5;
  const int b    = blockIdx.x * 2 + smp;
  const int sbase = smp * SSTRIDE;

  int cls, u;
  if (lane < 15)      { cls = 0; u = lane; }
  else if (lane < 25) { cls = 1; u = lane - 15; }
  else if (lane < 27) { cls = 2; u = lane - 25; }
  else                { cls = 3; u = lane - 27; }   // x-loader

  const int  woff   = (cls == 0) ? 0 : (cls == 1) ? 8 : (cls == 2) ? 24 : 0;
  const int  wpos   = (cls == 0) ? 8 + u : (cls == 1) ? 24 + u
                    : (cls == 2) ? 36 + u : u;
  const int  istart = cls;            // suppress h-update until layer's first step
  const bool is_x   = (cls == 3);
  const bool is_o   = (cls == 2);
  const int  xj     = is_x ? u : 0;   // in-bounds x column for everyone

  // ---- per-lane padded weight vectors (zero outside class's inputs) ----
  float Wr[28], Wz[28], Wnx[28], Wnh[28];
#pragma unroll
  for (int j = 0; j < 28; ++j) { Wr[j] = 0.f; Wz[j] = 0.f; Wnx[j] = 0.f; Wnh[j] = 0.f; }
  float br = 0.f, bz = 0.f, bnx = 0.f, bnh = 0.f;

  if (cls == 0) {
#pragma unroll
    for (int j = 0; j < 5; ++j) {
      Wr [j] = w_ih0[(u         ) * 5 + j] * L2E;
      Wz [j] = w_ih0[(H0 + u    ) * 5 + j] * L2E;
      Wnx[j] = w_ih0[(2 * H0 + u) * 5 + j] * L2E2;
    }
#pragma unroll
    for (int k = 0; k < 15; ++k) {
      Wr [8 + k] = w_hh0[(u         ) * 15 + k] * L2E;
      Wz [8 + k] = w_hh0[(H0 + u    ) * 15 + k] * L2E;
      Wnh[8 + k] = w_hh0[(2 * H0 + u) * 15 + k] * L2E2;
    }
    br  = (b_ih0[u] + b_hh0[u]) * L2E;
    bz  = (b_ih0[H0 + u] + b_hh0[H0 + u]) * L2E;
    bnx = b_ih0[2 * H0 + u] * L2E2;
    bnh = b_hh0[2 * H0 + u] * L2E2;
  } else if (cls == 1) {
#pragma unroll
    for (int k = 0; k < 15; ++k) {
      Wr [k] = w_ih1[(u         ) * 15 + k] * L2E;
      Wz [k] = w_ih1[(H1 + u    ) * 15 + k] * L2E;
      Wnx[k] = w_ih1[(2 * H1 + u) * 15 + k] * L2E2;
    }
#pragma unroll
    for (int k = 0; k < 10; ++k) {
      Wr [16 + k] = w_hh1[(u         ) * 10 + k] * L2E;
      Wz [16 + k] = w_hh1[(H1 + u    ) * 10 + k] * L2E;
      Wnh[16 + k] = w_hh1[(2 * H1 + u) * 10 + k] * L2E2;
    }
    br  = (b_ih1[u] + b_hh1[u]) * L2E;
    bz  = (b_ih1[H1 + u] + b_hh1[H1 + u]) * L2E;
    bnx = b_ih1[2 * H1 + u] * L2E2;
    bnh = b_hh1[2 * H1 + u] * L2E2;
  } else if (cls == 2) {
#pragma unroll
    for (int k = 0; k < 10; ++k) {
      Wr [k] = w_ih2[(u         ) * 10 + k] * L2E;
      Wz [k] = w_ih2[(H2 + u    ) * 10 + k] * L2E;
      Wnx[k] = w_ih2[(2 * H2 + u) * 10 + k] * L2E2;
    }
#pragma unroll
    for (int k = 0; k < 2; ++k) {
      Wr [12 + k] = w_hh2[(u         ) * 2 + k] * L2E;
      Wz [12 + k] = w_hh2[(H2 + u    ) * 2 + k] * L2E;
      Wnh[12 + k] = w_hh2[(2 * H2 + u) * 2 + k] * L2E2;
    }
    br  = (b_ih2[u] + b_hh2[u]) * L2E;
    bz  = (b_ih2[H2 + u] + b_hh2[H2 + u]) * L2E;
    bnx = b_ih2[2 * H2 + u] * L2E2;
    bnh = b_hh2[2 * H2 + u] * L2E2;
  }

  // Pack ONLY the pairs that are nonzero for at least one lane class:
  //   R: pairs 0..12   Z: pairs 0..12   Nx: pairs 0..7   Nh: pairs 4..12
  v2f WR2[13], WZ2[13], WNX2[8], WNH2[9];
#pragma unroll
  for (int j = 0; j < 13; ++j) {
    WR2[j] = (v2f){Wr[2 * j], Wr[2 * j + 1]};
    WZ2[j] = (v2f){Wz[2 * j], Wz[2 * j + 1]};
  }
#pragma unroll
  for (int j = 0; j < 8; ++j)  WNX2[j] = (v2f){Wnx[2 * j], Wnx[2 * j + 1]};
#pragma unroll
  for (int j = 0; j < 9; ++j)  WNH2[j] = (v2f){Wnh[2 * (j + 4)], Wnh[2 * (j + 4) + 1]};

  // Persistent bias pairs (C operand of each chain's first pk_fma -> no movs)
  const v2f BR = (v2f){br,  0.f};
  const v2f BZ = (v2f){bz,  0.f};
  const v2f BX = (v2f){bnx, 0.f};
  const v2f BH = (v2f){bnh, 0.f};
  const v2f Z2 = (v2f){0.f, 0.f};

  // ---- init staging (zeros = h(-1) states + pads), publish x(0) ----
  for (int j = tid; j < 112; j += 64) stage[j] = 0.0f;

  // 6-deep rotating x pipeline: at top of body I, xr{I%6} holds x(I+1)
  // (loaded 6 bodies ago); after publishing it, the same register receives
  // the load of row min(I+7, TT-1). 6 loads stay in flight.
  float xr0, xr1, xr2, xr3, xr4, xr5;
  const size_t xstep = (size_t)NB * 5;
  {
    const size_t base = (size_t)b * 5 + xj;
    const float x0 = x[base];                 // t=0
    xr0 = x[1 * xstep + base];
    xr1 = x[2 * xstep + base];
    xr2 = x[3 * xstep + base];
    xr3 = x[4 * xstep + base];
    xr4 = x[5 * xstep + base];
    xr5 = x[6 * xstep + base];
    if (is_x) stage[sbase + u] = x0;
  }
  __builtin_amdgcn_wave_barrier();

  float h = 0.0f;
  const float* wbase = &stage[sbase + woff];
  const v4f* wloc = (const v4f*)wbase;
  float* pub = &stage[sbase + wpos];

  const float* xp = x + (size_t)7 * xstep + (size_t)b * 5 + xj;
  float* op = out + (size_t)b * H2 + (is_o ? u : 0);  // t = i-2 target
  const size_t ostep = (size_t)NB * H2;

// One skewed-pipeline GRU step.
//   I       : step index (compile-time in prologue, i+k in the loop)
//   XR      : rotating x register (holds x(I+1); reloaded with row I+7)
//   HGUARD  : true only for I=0,1 (istart suppression needed)
//   DOSTORE : I>=2 (store t=I-2 and advance op)
//   DOADV   : advance xp iff I+8 < TT (clamps trailing loads to row TT-1)
// Pair->window map: P0=q0.lo P1=q0.hi P2=q1.lo P3=q1.hi P4=q2.lo P5=q2.hi
// P6=q3.lo P7=q3.hi P8=q4.lo P9=q4.hi P10=q5.lo P11=q5.hi P12=q6.
#define GRU_STEP(I, XR, HGUARD, DOSTORE, DOADV)                           \
  {                                                                       \
    const v4f q0 = wloc[0], q1 = wloc[1], q2 = wloc[2], q3 = wloc[3];     \
    const v4f q4 = wloc[4], q5 = wloc[5];                                 \
    const v2f q6 = ((const v2f*)wbase)[12];                               \
    /* R: 3 chains 5+4+4 (bias in chain 0's C) */                         \
    v2f aR0 = pk_fma(WR2[0],  q0.lo, BR);                                 \
    v2f aR1 = pk_fma(WR2[5],  q2.hi, Z2);                                 \
    v2f aR2 = pk_fma(WR2[9],  q4.hi, Z2);                                 \
    aR0 = pk_fma(WR2[1],  q0.hi, aR0);                                    \
    aR1 = pk_fma(WR2[6],  q3.lo, aR1);                                    \
    aR2 = pk_fma(WR2[10], q5.lo, aR2);                                    \
    aR0 = pk_fma(WR2[2],  q1.lo, aR0);                                    \
    aR1 = pk_fma(WR2[7],  q3.hi, aR1);                                    \
    aR2 = pk_fma(WR2[11], q5.hi, aR2);                                    \
    aR0 = pk_fma(WR2[3],  q1.hi, aR0);                                    \
    aR1 = pk_fma(WR2[8],  q4.lo, aR1);                                    \
    aR2 = pk_fma(WR2[12], q6,    aR2);                                    \
    aR0 = pk_fma(WR2[4],  q2.lo, aR0);                                    \
    /* Z: same split */                                                   \
    v2f aZ0 = pk_fma(WZ2[0],  q0.lo, BZ);                                 \
    v2f aZ1 = pk_fma(WZ2[5],  q2.hi, Z2);                                 \
    v2f aZ2 = pk_fma(WZ2[9],  q4.hi, Z2);                                 \
    aZ0 = pk_fma(WZ2[1],  q0.hi, aZ0);                                    \
    aZ1 = pk_fma(WZ2[6],  q3.lo, aZ1);                                    \
    aZ2 = pk_fma(WZ2[10], q5.lo, aZ2);                                    \
    aZ0 = pk_fma(WZ2[2],  q1.lo, aZ0);                                    \
    aZ1 = pk_fma(WZ2[7],  q3.hi, aZ1);                                    \
    aZ2 = pk_fma(WZ2[11], q5.hi, aZ2);                                    \
    aZ0 = pk_fma(WZ2[3],  q1.hi, aZ0);                                    \
    aZ1 = pk_fma(WZ2[8],  q4.lo, aZ1);                                    \
    aZ2 = pk_fma(WZ2[12], q6,    aZ2);                                    \
    aZ0 = pk_fma(WZ2[4],  q2.lo, aZ0);                                    \
    /* Nx: 2 chains 4+4 */                                                \
    v2f aX0 = pk_fma(WNX2[0], q0.lo, BX);                                 \
    v2f aX1 = pk_fma(WNX2[4], q2.lo, Z2);                                 \
    aX0 = pk_fma(WNX2[1], q0.hi, aX0);                                    \
    aX1 = pk_fma(WNX2[5], q2.hi, aX1);                                    \
    aX0 = pk_fma(WNX2[2], q1.lo, aX0);                                    \
    aX1 = pk_fma(WNX2[6], q3.lo, aX1);                                    \
    aX0 = pk_fma(WNX2[3], q1.hi, aX0);                                    \
    aX1 = pk_fma(WNX2[7], q3.hi, aX1);                                    \
    /* Nh: 2 chains 5+4 (WNH2[j] = pair j+4) */                           \
    v2f aH0 = pk_fma(WNH2[0], q2.lo, BH);                                 \
    v2f aH1 = pk_fma(WNH2[5], q4.hi, Z2);                                 \
    aH0 = pk_fma(WNH2[1], q2.hi, aH0);                                    \
    aH1 = pk_fma(WNH2[6], q5.lo, aH1);                                    \
    aH0 = pk_fma(WNH2[2], q3.lo, aH0);                                    \
    aH1 = pk_fma(WNH2[7], q5.hi, aH1);                                    \
    aH0 = pk_fma(WNH2[3], q3.hi, aH0);                                    \
    aH1 = pk_fma(WNH2[8], q6,    aH1);                                    \
    aH0 = pk_fma(WNH2[4], q4.lo, aH0);                                    \
    const float sR  = ((aR0.x + aR0.y) + (aR1.x + aR1.y)) + (aR2.x + aR2.y); \
    const float sZ  = ((aZ0.x + aZ0.y) + (aZ1.x + aZ1.y)) + (aZ2.x + aZ2.y); \
    const float sNx = (aX0.x + aX0.y) + (aX1.x + aX1.y);                  \
    const float sNh = (aH0.x + aH0.y) + (aH1.x + aH1.y);                  \
    const float r = sigm_p(sR);                                           \
    const float z = sigm_p(sZ);                                           \
    const float n = tanh_p(sNx + r * sNh);                                \
    const float hnew = n + z * (h - n);                                   \
    if (HGUARD) h = ((I) >= istart) ? hnew : h;                           \
    else        h = hnew;                                                 \
    *pub = is_x ? (XR) : h;          /* publish h (units) or x(I+1) */    \
    if (DOSTORE) {                                                        \
      if (is_o) *op = h;             /* t = I-2, exec-masked */           \
      op += ostep;                                                        \
    }                                                                     \
    XR = *xp;                        /* reload with row min(I+7, TT-1) */ \
    if (DOADV) xp += xstep;                                               \
    __builtin_amdgcn_wave_barrier(); /* next reads after publishes */     \
  }

  // Prologue: I = 0..5 (static guards; all advance xp).
  GRU_STEP(0, xr0, true,  false, true)
  GRU_STEP(1, xr1, true,  false, true)
  GRU_STEP(2, xr2, false, true,  true)
  GRU_STEP(3, xr3, false, true,  true)
  GRU_STEP(4, xr4, false, true,  true)
  GRU_STEP(5, xr5, false, true,  true)

  // Steady + tail: i = 6..1025 in 170 unroll-6 packs (1020 bodies).
  // Stores always on; xp advance clamps at row TT-1 (runtime scalar check).
#pragma unroll 1
  for (int i = 6; i < TT + 2; i += 6) {
    GRU_STEP(i + 0, xr0, false, true, (i + 0 + 8 < TT))
    GRU_STEP(i + 1, xr1, false, true, (i + 1 + 8 < TT))
    GRU_STEP(i + 2, xr2, false, true, (i + 2 + 8 < TT))
    GRU_STEP(i + 3, xr3, false, true, (i + 3 + 8 < TT))
    GRU_STEP(i + 4, xr4, false, true, (i + 4 + 8 < TT))
    GRU_STEP(i + 5, xr5, false, true, (i + 5 + 8 < TT))
  }

#undef GRU_STEP
}

extern "C" void kernel_launch(void* const* d_in, const int* in_sizes, int n_in,
                              void* d_out, int out_size, void* d_ws, size_t ws_size,
                              hipStream_t stream) {
  (void)in_sizes; (void)n_in; (void)d_ws; (void)ws_size; (void)out_size;
  const float* x     = (const float*)d_in[0];
  const float* w_ih0 = (const float*)d_in[1];
  const float* w_hh0 = (const float*)d_in[2];
  const float* b_ih0 = (const float*)d_in[3];
  const float* b_hh0 = (const float*)d_in[4];
  const float* w_ih1 = (const float*)d_in[5];
  const float* w_hh1 = (const float*)d_in[6];
  const float* b_ih1 = (const float*)d_in[7];
  const float* b_hh1 = (const float*)d_in[8];
  const float* w_ih2 = (const float*)d_in[9];
  const float* w_hh2 = (const float*)d_in[10];
  const float* b_ih2 = (const float*)d_in[11];
  const float* b_hh2 = (const float*)d_in[12];
  float* out = (float*)d_out;

  gru3_fused<<<NB / 2, 64, 0, stream>>>(
      x, w_ih0, w_hh0, b_ih0, b_hh0,
      w_ih1, w_hh1, b_ih1, b_hh1,
      w_ih2, w_hh2, b_ih2, b_hh2, out);
}

// Round 5
// 515.858 us; speedup vs baseline: 1.3628x; 1.0055x over previous
//
#include <hip/hip_runtime.h>

namespace {

constexpr int TT = 1024;   // timesteps
constexpr int NB = 4096;   // batch
constexpr int H0 = 15, H1 = 10, H2 = 2;

// Pre-scales so activations use v_exp_f32 (exp2) directly:
// sigmoid(v) = 1/(1+exp2(-v*L2E)); tanh(u) = 2/(1+exp2(-u*2*L2E)) - 1.
constexpr float L2E  = 1.44269504088896340736f;
constexpr float L2E2 = 2.88539008177792681472f;

// Staging vector per sample (floats): x[0..4] pad[5..7] h0[8..22] pad[23]
// h1[24..33] pad[34..35] h2[36..37] pad[38..47].  Window starts (16B-aligned):
// L0 -> 0 (x+h0), L1 -> 8 (h0+h1), L2 -> 24 (h1+h2). Window = 26 floats used.
constexpr int SSTRIDE = 48;

typedef float v2f __attribute__((ext_vector_type(2)));
typedef float v4f __attribute__((ext_vector_type(4)));

__device__ __forceinline__ float frcp(float v)  { return __builtin_amdgcn_rcpf(v); }
__device__ __forceinline__ float fexp2(float v) { return __builtin_amdgcn_exp2f(v); }
__device__ __forceinline__ float sigm_p(float v) { return frcp(1.0f + fexp2(-v)); }
__device__ __forceinline__ float tanh_p(float u) {
  return __builtin_fmaf(2.0f, frcp(1.0f + fexp2(-u)), -1.0f);
}

// Guaranteed packed FMA: d = a*b + c on both halves (v_pk_fma_f32).
__device__ __forceinline__ v2f pk_fma(v2f a, v2f b, v2f c) {
  v2f d;
  asm("v_pk_fma_f32 %0, %1, %2, %3" : "=v"(d) : "v"(a), "v"(b), "v"(c));
  return d;
}

}  // namespace

// Grid: 2048 blocks x 64 threads = 2 waves/SIMD (grid-limited). Wave = 2
// samples x 32 lanes. Per sample: lanes 0-14 = L0 units, 15-24 = L1 units,
// 25-26 = L2 units, 27-31 = x-loaders. Layers skewed (iter i: L0(i), L1(i-1),
// L2(i-2)) -> one publish/iteration. Single-wave block: wave-lockstep +
// in-order DS pipe; wave_barrier pins compiler ordering.
//
// This revision: PIN THE WINDOW IN REGISTERS. rocprof shows the allocator
// settles at 100 VGPR even with a 256-reg budget (launch_bounds(64,2) and
// waves_per_eu(2,2) both left VGPR_Count at 100) while the working set is
// ~150 regs -> it must be re-phasing/re-reading the LDS window (or shuttling
// through movs), exposing LDS latency several times per iteration. Fix at
// source level: the 7 window loads are inline-asm ds_read_b128/b64 with
// early-clobber outputs, ONE explicit s_waitcnt lgkmcnt(0), and
// sched_barrier(0) (guide rule #18). The compiler cannot re-issue or
// re-phase them; all 26 floats stay live through the MAC block.
//   + x-load / out-store via scalar-base + u32 voffset (1 VALU advance).
//   + everything else identical to the 460us round-4 kernel.
extern "C" __global__ __launch_bounds__(64)
__attribute__((amdgpu_waves_per_eu(2, 2)))
void gru3_fused(
    const float* __restrict__ x,
    const float* __restrict__ w_ih0, const float* __restrict__ w_hh0,
    const float* __restrict__ b_ih0, const float* __restrict__ b_hh0,
    const float* __restrict__ w_ih1, const float* __restrict__ w_hh1,
    const float* __restrict__ b_ih1, const float* __restrict__ b_hh1,
    const float* __restrict__ w_ih2, const float* __restrict__ w_hh2,
    const float* __restrict__ b_ih2, const float* __restrict__ b_hh2,
    float* __restrict__ out) {
  // 2 samples * 48 + tail pad so L2's window over-read stays in-buffer.
  __shared__ __attribute__((aligned(16))) float stage[112];

  const int tid  = threadIdx.x;
  const int lane = tid & 31;
  const int smp  = tid >> 5;
  const int b    = blockIdx.x * 2 + smp;
  const int sbase = smp * SSTRIDE;

  int cls, u;
  if (lane < 15)      { cls = 0; u = lane; }
  else if (lane < 25) { cls = 1; u = lane - 15; }
  else if (lane < 27) { cls = 2; u = lane - 25; }
  else                { cls = 3; u = lane - 27; }   // x-loader

  const int  woff   = (cls == 0) ? 0 : (cls == 1) ? 8 : (cls == 2) ? 24 : 0;
  const int  wpos   = (cls == 0) ? 8 + u : (cls == 1) ? 24 + u
                    : (cls == 2) ? 36 + u : u;
  const int  istart = cls;            // suppress h-update until layer's first step
  const bool is_x   = (cls == 3);
  const bool is_o   = (cls == 2);
  const int  xj     = is_x ? u : 0;   // in-bounds x column for everyone

  // ---- per-lane padded weight vectors (zero outside class's inputs) ----
  float Wr[28], Wz[28], Wnx[28], Wnh[28];
#pragma unroll
  for (int j = 0; j < 28; ++j) { Wr[j] = 0.f; Wz[j] = 0.f; Wnx[j] = 0.f; Wnh[j] = 0.f; }
  float br = 0.f, bz = 0.f, bnx = 0.f, bnh = 0.f;

  if (cls == 0) {
#pragma unroll
    for (int j = 0; j < 5; ++j) {
      Wr [j] = w_ih0[(u         ) * 5 + j] * L2E;
      Wz [j] = w_ih0[(H0 + u    ) * 5 + j] * L2E;
      Wnx[j] = w_ih0[(2 * H0 + u) * 5 + j] * L2E2;
    }
#pragma unroll
    for (int k = 0; k < 15; ++k) {
      Wr [8 + k] = w_hh0[(u         ) * 15 + k] * L2E;
      Wz [8 + k] = w_hh0[(H0 + u    ) * 15 + k] * L2E;
      Wnh[8 + k] = w_hh0[(2 * H0 + u) * 15 + k] * L2E2;
    }
    br  = (b_ih0[u] + b_hh0[u]) * L2E;
    bz  = (b_ih0[H0 + u] + b_hh0[H0 + u]) * L2E;
    bnx = b_ih0[2 * H0 + u] * L2E2;
    bnh = b_hh0[2 * H0 + u] * L2E2;
  } else if (cls == 1) {
#pragma unroll
    for (int k = 0; k < 15; ++k) {
      Wr [k] = w_ih1[(u         ) * 15 + k] * L2E;
      Wz [k] = w_ih1[(H1 + u    ) * 15 + k] * L2E;
      Wnx[k] = w_ih1[(2 * H1 + u) * 15 + k] * L2E2;
    }
#pragma unroll
    for (int k = 0; k < 10; ++k) {
      Wr [16 + k] = w_hh1[(u         ) * 10 + k] * L2E;
      Wz [16 + k] = w_hh1[(H1 + u    ) * 10 + k] * L2E;
      Wnh[16 + k] = w_hh1[(2 * H1 + u) * 10 + k] * L2E2;
    }
    br  = (b_ih1[u] + b_hh1[u]) * L2E;
    bz  = (b_ih1[H1 + u] + b_hh1[H1 + u]) * L2E;
    bnx = b_ih1[2 * H1 + u] * L2E2;
    bnh = b_hh1[2 * H1 + u] * L2E2;
  } else if (cls == 2) {
#pragma unroll
    for (int k = 0; k < 10; ++k) {
      Wr [k] = w_ih2[(u         ) * 10 + k] * L2E;
      Wz [k] = w_ih2[(H2 + u    ) * 10 + k] * L2E;
      Wnx[k] = w_ih2[(2 * H2 + u) * 10 + k] * L2E2;
    }
#pragma unroll
    for (int k = 0; k < 2; ++k) {
      Wr [12 + k] = w_hh2[(u         ) * 2 + k] * L2E;
      Wz [12 + k] = w_hh2[(H2 + u    ) * 2 + k] * L2E;
      Wnh[12 + k] = w_hh2[(2 * H2 + u) * 2 + k] * L2E2;
    }
    br  = (b_ih2[u] + b_hh2[u]) * L2E;
    bz  = (b_ih2[H2 + u] + b_hh2[H2 + u]) * L2E;
    bnx = b_ih2[2 * H2 + u] * L2E2;
    bnh = b_hh2[2 * H2 + u] * L2E2;
  }

  // Pack ONLY the pairs that are nonzero for at least one lane class:
  //   R: pairs 0..12   Z: pairs 0..12   Nx: pairs 0..7   Nh: pairs 4..12
  v2f WR2[13], WZ2[13], WNX2[8], WNH2[9];
#pragma unroll
  for (int j = 0; j < 13; ++j) {
    WR2[j] = (v2f){Wr[2 * j], Wr[2 * j + 1]};
    WZ2[j] = (v2f){Wz[2 * j], Wz[2 * j + 1]};
  }
#pragma unroll
  for (int j = 0; j < 8; ++j)  WNX2[j] = (v2f){Wnx[2 * j], Wnx[2 * j + 1]};
#pragma unroll
  for (int j = 0; j < 9; ++j)  WNH2[j] = (v2f){Wnh[2 * (j + 4)], Wnh[2 * (j + 4) + 1]};

  // Persistent bias pairs (C operand of each chain's first pk_fma -> no movs)
  const v2f BR = (v2f){br,  0.f};
  const v2f BZ = (v2f){bz,  0.f};
  const v2f BX = (v2f){bnx, 0.f};
  const v2f BH = (v2f){bnh, 0.f};
  const v2f Z2 = (v2f){0.f, 0.f};

  // ---- init staging (zeros = h(-1) states + pads), publish x(0) ----
  for (int j = tid; j < 112; j += 64) stage[j] = 0.0f;

  // 6-deep rotating x pipeline: at top of body I, xr{I%6} holds x(I+1)
  // (loaded 6 bodies ago); after publishing it, the same register receives
  // the load of row min(I+7, TT-1). 6 loads stay in flight.
  float xr0, xr1, xr2, xr3, xr4, xr5;
  const size_t xstep = (size_t)NB * 5;
  {
    const size_t base = (size_t)b * 5 + xj;
    const float x0 = x[base];                 // t=0
    xr0 = x[1 * xstep + base];
    xr1 = x[2 * xstep + base];
    xr2 = x[3 * xstep + base];
    xr3 = x[4 * xstep + base];
    xr4 = x[5 * xstep + base];
    xr5 = x[6 * xstep + base];
    if (is_x) stage[sbase + u] = x0;
  }
  __builtin_amdgcn_wave_barrier();

  float h = 0.0f;
  // LDS byte address of this lane's window (asm ds_read operand).
  const unsigned int wa =
      (unsigned int)(uintptr_t)(&stage[sbase + woff]);
  float* pub = &stage[sbase + wpos];

  // Scalar-base + u32-voffset addressing (1 VALU advance per step):
  //   x row min(I+7,TT-1):  addr = x + xvoff,  xvoff += NB*5*4
  //   out t=I-2:            addr = out + ovoff, ovoff += NB*H2*4
  unsigned int xvoff = (unsigned int)(((size_t)7 * xstep + (size_t)b * 5 + xj) * 4);
  unsigned int ovoff = (unsigned int)(((size_t)b * H2 + (is_o ? u : 0)) * 4);
  constexpr unsigned int XSTEPB = (unsigned int)(NB * 5 * 4);
  constexpr unsigned int OSTEPB = (unsigned int)(NB * H2 * 4);

// One skewed-pipeline GRU step.
//   I       : step index (compile-time in prologue, i+k in the loop)
//   XR      : rotating x register (holds x(I+1); reloaded with row I+7)
//   HGUARD  : true only for I=0,1 (istart suppression needed)
//   DOSTORE : I>=2 (store t=I-2 and advance ovoff)
//   DOADV   : advance xvoff iff I+8 < TT (clamps trailing loads to row TT-1)
// Window read is pinned: 6x ds_read_b128 + 1x ds_read_b64 as inline asm
// (early-clobber outs), one s_waitcnt lgkmcnt(0), sched_barrier(0) -- the
// compiler cannot re-phase or re-issue these reads (rule #18 fence).
// Pair->window map: P0=q0.lo P1=q0.hi P2=q1.lo P3=q1.hi P4=q2.lo P5=q2.hi
// P6=q3.lo P7=q3.hi P8=q4.lo P9=q4.hi P10=q5.lo P11=q5.hi P12=q6.
#define GRU_STEP(I, XR, HGUARD, DOSTORE, DOADV)                           \
  {                                                                       \
    v4f q0, q1, q2, q3, q4, q5; v2f q6;                                   \
    asm volatile(                                                         \
        "ds_read_b128 %0, %7 offset:0\n\t"                                \
        "ds_read_b128 %1, %7 offset:16\n\t"                               \
        "ds_read_b128 %2, %7 offset:32\n\t"                               \
        "ds_read_b128 %3, %7 offset:48\n\t"                               \
        "ds_read_b128 %4, %7 offset:64\n\t"                               \
        "ds_read_b128 %5, %7 offset:80\n\t"                               \
        "ds_read_b64  %6, %7 offset:96"                                   \
        : "=&v"(q0), "=&v"(q1), "=&v"(q2), "=&v"(q3), "=&v"(q4),          \
          "=&v"(q5), "=&v"(q6)                                            \
        : "v"(wa));                                                       \
    asm volatile("s_waitcnt lgkmcnt(0)" ::: "memory");                    \
    __builtin_amdgcn_sched_barrier(0);                                    \
    /* R: 3 chains 5+4+4 (bias in chain 0's C) */                         \
    v2f aR0 = pk_fma(WR2[0],  q0.lo, BR);                                 \
    v2f aR1 = pk_fma(WR2[5],  q2.hi, Z2);                                 \
    v2f aR2 = pk_fma(WR2[9],  q4.hi, Z2);                                 \
    aR0 = pk_fma(WR2[1],  q0.hi, aR0);                                    \
    aR1 = pk_fma(WR2[6],  q3.lo, aR1);                                    \
    aR2 = pk_fma(WR2[10], q5.lo, aR2);                                    \
    aR0 = pk_fma(WR2[2],  q1.lo, aR0);                                    \
    aR1 = pk_fma(WR2[7],  q3.hi, aR1);                                    \
    aR2 = pk_fma(WR2[11], q5.hi, aR2);                                    \
    aR0 = pk_fma(WR2[3],  q1.hi, aR0);                                    \
    aR1 = pk_fma(WR2[8],  q4.lo, aR1);                                    \
    aR2 = pk_fma(WR2[12], q6,    aR2);                                    \
    aR0 = pk_fma(WR2[4],  q2.lo, aR0);                                    \
    /* Z: same split */                                                   \
    v2f aZ0 = pk_fma(WZ2[0],  q0.lo, BZ);                                 \
    v2f aZ1 = pk_fma(WZ2[5],  q2.hi, Z2);                                 \
    v2f aZ2 = pk_fma(WZ2[9],  q4.hi, Z2);                                 \
    aZ0 = pk_fma(WZ2[1],  q0.hi, aZ0);                                    \
    aZ1 = pk_fma(WZ2[6],  q3.lo, aZ1);                                    \
    aZ2 = pk_fma(WZ2[10], q5.lo, aZ2);                                    \
    aZ0 = pk_fma(WZ2[2],  q1.lo, aZ0);                                    \
    aZ1 = pk_fma(WZ2[7],  q3.hi, aZ1);                                    \
    aZ2 = pk_fma(WZ2[11], q5.hi, aZ2);                                    \
    aZ0 = pk_fma(WZ2[3],  q1.hi, aZ0);                                    \
    aZ1 = pk_fma(WZ2[8],  q4.lo, aZ1);                                    \
    aZ2 = pk_fma(WZ2[12], q6,    aZ2);                                    \
    aZ0 = pk_fma(WZ2[4],  q2.lo, aZ0);                                    \
    /* Nx: 2 chains 4+4 */                                                \
    v2f aX0 = pk_fma(WNX2[0], q0.lo, BX);                                 \
    v2f aX1 = pk_fma(WNX2[4], q2.lo, Z2);                                 \
    aX0 = pk_fma(WNX2[1], q0.hi, aX0);                                    \
    aX1 = pk_fma(WNX2[5], q2.hi, aX1);                                    \
    aX0 = pk_fma(WNX2[2], q1.lo, aX0);                                    \
    aX1 = pk_fma(WNX2[6], q3.lo, aX1);                                    \
    aX0 = pk_fma(WNX2[3], q1.hi, aX0);                                    \
    aX1 = pk_fma(WNX2[7], q3.hi, aX1);                                    \
    /* Nh: 2 chains 5+4 (WNH2[j] = pair j+4) */                           \
    v2f aH0 = pk_fma(WNH2[0], q2.lo, BH);                                 \
    v2f aH1 = pk_fma(WNH2[5], q4.hi, Z2);                                 \
    aH0 = pk_fma(WNH2[1], q2.hi, aH0);                                    \
    aH1 = pk_fma(WNH2[6], q5.lo, aH1);                                    \
    aH0 = pk_fma(WNH2[2], q3.lo, aH0);                                    \
    aH1 = pk_fma(WNH2[7], q5.hi, aH1);                                    \
    aH0 = pk_fma(WNH2[3], q3.hi, aH0);                                    \
    aH1 = pk_fma(WNH2[8], q6,    aH1);                                    \
    aH0 = pk_fma(WNH2[4], q4.lo, aH0);                                    \
    const float sR  = ((aR0.x + aR0.y) + (aR1.x + aR1.y)) + (aR2.x + aR2.y); \
    const float sZ  = ((aZ0.x + aZ0.y) + (aZ1.x + aZ1.y)) + (aZ2.x + aZ2.y); \
    const float sNx = (aX0.x + aX0.y) + (aX1.x + aX1.y);                  \
    const float sNh = (aH0.x + aH0.y) + (aH1.x + aH1.y);                  \
    const float r = sigm_p(sR);                                           \
    const float z = sigm_p(sZ);                                           \
    const float n = tanh_p(sNx + r * sNh);                                \
    const float hnew = n + z * (h - n);                                   \
    if (HGUARD) h = ((I) >= istart) ? hnew : h;                           \
    else        h = hnew;                                                 \
    *pub = is_x ? (XR) : h;          /* publish h (units) or x(I+1) */    \
    if (DOSTORE) {                                                        \
      if (is_o)                                                           \
        *(float*)((char*)out + ovoff) = h;   /* t = I-2, exec-masked */   \
      ovoff += OSTEPB;                                                    \
    }                                                                     \
    XR = *(const float*)((const char*)x + xvoff); /* row min(I+7,TT-1) */ \
    if (DOADV) xvoff += XSTEPB;                                           \
    __builtin_amdgcn_wave_barrier(); /* next reads after publishes */     \
  }

  // Prologue: I = 0..5 (static guards; all advance xvoff).
  GRU_STEP(0, xr0, true,  false, true)
  GRU_STEP(1, xr1, true,  false, true)
  GRU_STEP(2, xr2, false, true,  true)
  GRU_STEP(3, xr3, false, true,  true)
  GRU_STEP(4, xr4, false, true,  true)
  GRU_STEP(5, xr5, false, true,  true)

  // Steady + tail: i = 6..1025 in 170 unroll-6 packs (1020 bodies).
  // Stores always on; xvoff advance clamps at row TT-1 (uniform check).
#pragma unroll 1
  for (int i = 6; i < TT + 2; i += 6) {
    GRU_STEP(i + 0, xr0, false, true, (i + 0 + 8 < TT))
    GRU_STEP(i + 1, xr1, false, true, (i + 1 + 8 < TT))
    GRU_STEP(i + 2, xr2, false, true, (i + 2 + 8 < TT))
    GRU_STEP(i + 3, xr3, false, true, (i + 3 + 8 < TT))
    GRU_STEP(i + 4, xr4, false, true, (i + 4 + 8 < TT))
    GRU_STEP(i + 5, xr5, false, true, (i + 5 + 8 < TT))
  }

#undef GRU_STEP
}

extern "C" void kernel_launch(void* const* d_in, const int* in_sizes, int n_in,
                              void* d_out, int out_size, void* d_ws, size_t ws_size,
                              hipStream_t stream) {
  (void)in_sizes; (void)n_in; (void)d_ws; (void)ws_size; (void)out_size;
  const float* x     = (const float*)d_in[0];
  const float* w_ih0 = (const float*)d_in[1];
  const float* w_hh0 = (const float*)d_in[2];
  const float* b_ih0 = (const float*)d_in[3];
  const float* b_hh0 = (const float*)d_in[4];
  const float* w_ih1 = (const float*)d_in[5];
  const float* w_hh1 = (const float*)d_in[6];
  const float* b_ih1 = (const float*)d_in[7];
  const float* b_hh1 = (const float*)d_in[8];
  const float* w_ih2 = (const float*)d_in[9];
  const float* w_hh2 = (const float*)d_in[10];
  const float* b_ih2 = (const float*)d_in[11];
  const float* b_hh2 = (const float*)d_in[12];
  float* out = (float*)d_out;

  gru3_fused<<<NB / 2, 64, 0, stream>>>(
      x, w_ih0, w_hh0, b_ih0, b_hh0,
      w_ih1, w_hh1, b_ih1, b_hh1,
      w_ih2, w_hh2, b_ih2, b_hh2, out);
}

// Round 6
// 503.516 us; speedup vs baseline: 1.3963x; 1.0245x over previous
//
#include <hip/hip_runtime.h>

namespace {

constexpr int TT = 1024;   // timesteps
constexpr int NB = 4096;   // batch
constexpr int H0 = 15, H1 = 10, H2 = 2;

// Pre-scales so activations use v_exp_f32 (exp2) directly:
// sigmoid(v) = 1/(1+exp2(-v*L2E)); tanh(u) = 2/(1+exp2(-u*2*L2E)) - 1.
constexpr float L2E  = 1.44269504088896340736f;
constexpr float L2E2 = 2.88539008177792681472f;

// Staging vector per sample (floats): x[0..4] pad[5..7] h0[8..22] pad[23]
// h1[24..33] pad[34..35] h2[36..37] pad[38..47].  Window starts (16B-aligned):
// L0 -> 0 (x+h0), L1 -> 8 (h0+h1), L2 -> 24 (h1+h2). Window = 26 floats used.
constexpr int SSTRIDE = 48;

typedef float v2f __attribute__((ext_vector_type(2)));
typedef float v4f __attribute__((ext_vector_type(4)));

__device__ __forceinline__ float frcp(float v)  { return __builtin_amdgcn_rcpf(v); }
__device__ __forceinline__ float fexp2(float v) { return __builtin_amdgcn_exp2f(v); }
__device__ __forceinline__ float sigm_p(float v) { return frcp(1.0f + fexp2(-v)); }
__device__ __forceinline__ float tanh_p(float u) {
  return __builtin_fmaf(2.0f, frcp(1.0f + fexp2(-u)), -1.0f);
}

// Guaranteed packed FMA: d = a*b + c on both halves (v_pk_fma_f32).
__device__ __forceinline__ v2f pk_fma(v2f a, v2f b, v2f c) {
  v2f d;
  asm("v_pk_fma_f32 %0, %1, %2, %3" : "=v"(d) : "v"(a), "v"(b), "v"(c));
  return d;
}

}  // namespace

// Grid: 2048 blocks x 64 threads = 2 waves/SIMD (grid-limited). Wave = 2
// samples x 32 lanes. Per sample: lanes 0-14 = L0 units, 15-24 = L1 units,
// 25-26 = L2 units, 27-31 = x-loaders. Layers skewed (iter i: L0(i), L1(i-1),
// L2(i-2)) -> one publish/iteration. Single-wave block: wave-lockstep +
// in-order DS pipe; wave_barrier pins compiler ordering.
//
// This revision: EARLY-ISSUE THE WINDOW READS. Previously the 7 ds_reads
// were issued at the top of each body with s_waitcnt lgkmcnt(0) immediately
// after -> the full LDS round-trip (~120 cyc) was exposed every iteration
// (and the 2 waves/SIMD tend to stall together). Now the reads for body I+1
// are issued at the END of body I, right after the publish ds_write (same
// wave, in-order DS pipe guarantees write-before-read data delivery -- the
// same property the publish/read pair already relied on). The q registers
// are dead after the MAC block, so the early issue reuses them with ZERO
// extra register pressure. LDS latency now overlaps the out-store, x-load
// issue, and loop bookkeeping instead of stalling the wave.
//   Ordering pins: wave_barrier between publish and read-issue;
//   s_waitcnt lgkmcnt(0) + sched_barrier(0) before the MACs (rule #18).
extern "C" __global__ __launch_bounds__(64)
__attribute__((amdgpu_waves_per_eu(2, 2)))
void gru3_fused(
    const float* __restrict__ x,
    const float* __restrict__ w_ih0, const float* __restrict__ w_hh0,
    const float* __restrict__ b_ih0, const float* __restrict__ b_hh0,
    const float* __restrict__ w_ih1, const float* __restrict__ w_hh1,
    const float* __restrict__ b_ih1, const float* __restrict__ b_hh1,
    const float* __restrict__ w_ih2, const float* __restrict__ w_hh2,
    const float* __restrict__ b_ih2, const float* __restrict__ b_hh2,
    float* __restrict__ out) {
  // 2 samples * 48 + tail pad so L2's window over-read stays in-buffer.
  __shared__ __attribute__((aligned(16))) float stage[112];

  const int tid  = threadIdx.x;
  const int lane = tid & 31;
  const int smp  = tid >> 5;
  const int b    = blockIdx.x * 2 + smp;
  const int sbase = smp * SSTRIDE;

  int cls, u;
  if (lane < 15)      { cls = 0; u = lane; }
  else if (lane < 25) { cls = 1; u = lane - 15; }
  else if (lane < 27) { cls = 2; u = lane - 25; }
  else                { cls = 3; u = lane - 27; }   // x-loader

  const int  woff   = (cls == 0) ? 0 : (cls == 1) ? 8 : (cls == 2) ? 24 : 0;
  const int  wpos   = (cls == 0) ? 8 + u : (cls == 1) ? 24 + u
                    : (cls == 2) ? 36 + u : u;
  const int  istart = cls;            // suppress h-update until layer's first step
  const bool is_x   = (cls == 3);
  const bool is_o   = (cls == 2);
  const int  xj     = is_x ? u : 0;   // in-bounds x column for everyone

  // ---- per-lane padded weight vectors (zero outside class's inputs) ----
  float Wr[28], Wz[28], Wnx[28], Wnh[28];
#pragma unroll
  for (int j = 0; j < 28; ++j) { Wr[j] = 0.f; Wz[j] = 0.f; Wnx[j] = 0.f; Wnh[j] = 0.f; }
  float br = 0.f, bz = 0.f, bnx = 0.f, bnh = 0.f;

  if (cls == 0) {
#pragma unroll
    for (int j = 0; j < 5; ++j) {
      Wr [j] = w_ih0[(u         ) * 5 + j] * L2E;
      Wz [j] = w_ih0[(H0 + u    ) * 5 + j] * L2E;
      Wnx[j] = w_ih0[(2 * H0 + u) * 5 + j] * L2E2;
    }
#pragma unroll
    for (int k = 0; k < 15; ++k) {
      Wr [8 + k] = w_hh0[(u         ) * 15 + k] * L2E;
      Wz [8 + k] = w_hh0[(H0 + u    ) * 15 + k] * L2E;
      Wnh[8 + k] = w_hh0[(2 * H0 + u) * 15 + k] * L2E2;
    }
    br  = (b_ih0[u] + b_hh0[u]) * L2E;
    bz  = (b_ih0[H0 + u] + b_hh0[H0 + u]) * L2E;
    bnx = b_ih0[2 * H0 + u] * L2E2;
    bnh = b_hh0[2 * H0 + u] * L2E2;
  } else if (cls == 1) {
#pragma unroll
    for (int k = 0; k < 15; ++k) {
      Wr [k] = w_ih1[(u         ) * 15 + k] * L2E;
      Wz [k] = w_ih1[(H1 + u    ) * 15 + k] * L2E;
      Wnx[k] = w_ih1[(2 * H1 + u) * 15 + k] * L2E2;
    }
#pragma unroll
    for (int k = 0; k < 10; ++k) {
      Wr [16 + k] = w_hh1[(u         ) * 10 + k] * L2E;
      Wz [16 + k] = w_hh1[(H1 + u    ) * 10 + k] * L2E;
      Wnh[16 + k] = w_hh1[(2 * H1 + u) * 10 + k] * L2E2;
    }
    br  = (b_ih1[u] + b_hh1[u]) * L2E;
    bz  = (b_ih1[H1 + u] + b_hh1[H1 + u]) * L2E;
    bnx = b_ih1[2 * H1 + u] * L2E2;
    bnh = b_hh1[2 * H1 + u] * L2E2;
  } else if (cls == 2) {
#pragma unroll
    for (int k = 0; k < 10; ++k) {
      Wr [k] = w_ih2[(u         ) * 10 + k] * L2E;
      Wz [k] = w_ih2[(H2 + u    ) * 10 + k] * L2E;
      Wnx[k] = w_ih2[(2 * H2 + u) * 10 + k] * L2E2;
    }
#pragma unroll
    for (int k = 0; k < 2; ++k) {
      Wr [12 + k] = w_hh2[(u         ) * 2 + k] * L2E;
      Wz [12 + k] = w_hh2[(H2 + u    ) * 2 + k] * L2E;
      Wnh[12 + k] = w_hh2[(2 * H2 + u) * 2 + k] * L2E2;
    }
    br  = (b_ih2[u] + b_hh2[u]) * L2E;
    bz  = (b_ih2[H2 + u] + b_hh2[H2 + u]) * L2E;
    bnx = b_ih2[2 * H2 + u] * L2E2;
    bnh = b_hh2[2 * H2 + u] * L2E2;
  }

  // Pack ONLY the pairs that are nonzero for at least one lane class:
  //   R: pairs 0..12   Z: pairs 0..12   Nx: pairs 0..7   Nh: pairs 4..12
  v2f WR2[13], WZ2[13], WNX2[8], WNH2[9];
#pragma unroll
  for (int j = 0; j < 13; ++j) {
    WR2[j] = (v2f){Wr[2 * j], Wr[2 * j + 1]};
    WZ2[j] = (v2f){Wz[2 * j], Wz[2 * j + 1]};
  }
#pragma unroll
  for (int j = 0; j < 8; ++j)  WNX2[j] = (v2f){Wnx[2 * j], Wnx[2 * j + 1]};
#pragma unroll
  for (int j = 0; j < 9; ++j)  WNH2[j] = (v2f){Wnh[2 * (j + 4)], Wnh[2 * (j + 4) + 1]};

  // Persistent bias pairs (C operand of each chain's first pk_fma -> no movs)
  const v2f BR = (v2f){br,  0.f};
  const v2f BZ = (v2f){bz,  0.f};
  const v2f BX = (v2f){bnx, 0.f};
  const v2f BH = (v2f){bnh, 0.f};
  const v2f Z2 = (v2f){0.f, 0.f};

  // ---- init staging (zeros = h(-1) states + pads), publish x(0) ----
  for (int j = tid; j < 112; j += 64) stage[j] = 0.0f;

  // 6-deep rotating x pipeline: at top of body I, xr{I%6} holds x(I+1)
  // (loaded 6 bodies ago); after publishing it, the same register receives
  // the load of row min(I+7, TT-1). 6 loads stay in flight.
  float xr0, xr1, xr2, xr3, xr4, xr5;
  const size_t xstep = (size_t)NB * 5;
  {
    const size_t base = (size_t)b * 5 + xj;
    const float x0 = x[base];                 // t=0
    xr0 = x[1 * xstep + base];
    xr1 = x[2 * xstep + base];
    xr2 = x[3 * xstep + base];
    xr3 = x[4 * xstep + base];
    xr4 = x[5 * xstep + base];
    xr5 = x[6 * xstep + base];
    if (is_x) stage[sbase + u] = x0;
  }

  float h = 0.0f;
  // LDS byte address of this lane's window (asm ds_read operand).
  const unsigned int wa =
      (unsigned int)(uintptr_t)(&stage[sbase + woff]);
  float* pub = &stage[sbase + wpos];

  // Scalar-base + u32-voffset addressing (1 VALU advance per step):
  //   x row min(I+7,TT-1):  addr = x + xvoff,  xvoff += NB*5*4
  //   out t=I-2:            addr = out + ovoff, ovoff += NB*H2*4
  unsigned int xvoff = (unsigned int)(((size_t)7 * xstep + (size_t)b * 5 + xj) * 4);
  unsigned int ovoff = (unsigned int)(((size_t)b * H2 + (is_o ? u : 0)) * 4);
  constexpr unsigned int XSTEPB = (unsigned int)(NB * 5 * 4);
  constexpr unsigned int OSTEPB = (unsigned int)(NB * H2 * 4);

  // Window registers: loop-carried. Written by READ_ISSUE at the END of
  // body I (after that body's publish), consumed by body I+1's MAC block
  // after the lgkmcnt(0) at its top.
  v4f q0, q1, q2, q3, q4, q5; v2f q6;

// Issue the 7 window reads for the NEXT body. Leading wave_barrier pins the
// issue after the preceding publish ds_write (in-order DS pipe then
// guarantees the reads see the freshly published values).
#define READ_ISSUE()                                                      \
    __builtin_amdgcn_wave_barrier();                                      \
    asm volatile(                                                         \
        "ds_read_b128 %0, %7 offset:0\n\t"                                \
        "ds_read_b128 %1, %7 offset:16\n\t"                               \
        "ds_read_b128 %2, %7 offset:32\n\t"                               \
        "ds_read_b128 %3, %7 offset:48\n\t"                               \
        "ds_read_b128 %4, %7 offset:64\n\t"                               \
        "ds_read_b128 %5, %7 offset:80\n\t"                               \
        "ds_read_b64  %6, %7 offset:96"                                   \
        : "=&v"(q0), "=&v"(q1), "=&v"(q2), "=&v"(q3), "=&v"(q4),          \
          "=&v"(q5), "=&v"(q6)                                            \
        : "v"(wa));

  // Prologue read-issue for body 0 (staging holds x(0) + zero states).
  __builtin_amdgcn_wave_barrier();
  READ_ISSUE();

// One skewed-pipeline GRU step.
//   I       : step index (compile-time in prologue, i+k in the loop)
//   XR      : rotating x register (holds x(I+1); reloaded with row I+7)
//   HGUARD  : true only for I=0,1 (istart suppression needed)
//   DOSTORE : I>=2 (store t=I-2 and advance ovoff)
//   DOADV   : advance xvoff iff I+8 < TT (clamps trailing loads to row TT-1)
// Top: wait for the reads issued by the PREVIOUS body (latency already
// mostly covered), sched_barrier fence (rule #18), then the MAC block.
// End: publish, then immediately issue next body's reads.
// Pair->window map: P0=q0.lo P1=q0.hi P2=q1.lo P3=q1.hi P4=q2.lo P5=q2.hi
// P6=q3.lo P7=q3.hi P8=q4.lo P9=q4.hi P10=q5.lo P11=q5.hi P12=q6.
#define GRU_STEP(I, XR, HGUARD, DOSTORE, DOADV)                           \
  {                                                                       \
    asm volatile("s_waitcnt lgkmcnt(0)" ::: "memory");                    \
    __builtin_amdgcn_sched_barrier(0);                                    \
    /* R: 3 chains 5+4+4 (bias in chain 0's C) */                         \
    v2f aR0 = pk_fma(WR2[0],  q0.lo, BR);                                 \
    v2f aR1 = pk_fma(WR2[5],  q2.hi, Z2);                                 \
    v2f aR2 = pk_fma(WR2[9],  q4.hi, Z2);                                 \
    aR0 = pk_fma(WR2[1],  q0.hi, aR0);                                    \
    aR1 = pk_fma(WR2[6],  q3.lo, aR1);                                    \
    aR2 = pk_fma(WR2[10], q5.lo, aR2);                                    \
    aR0 = pk_fma(WR2[2],  q1.lo, aR0);                                    \
    aR1 = pk_fma(WR2[7],  q3.hi, aR1);                                    \
    aR2 = pk_fma(WR2[11], q5.hi, aR2);                                    \
    aR0 = pk_fma(WR2[3],  q1.hi, aR0);                                    \
    aR1 = pk_fma(WR2[8],  q4.lo, aR1);                                    \
    aR2 = pk_fma(WR2[12], q6,    aR2);                                    \
    aR0 = pk_fma(WR2[4],  q2.lo, aR0);                                    \
    /* Z: same split */                                                   \
    v2f aZ0 = pk_fma(WZ2[0],  q0.lo, BZ);                                 \
    v2f aZ1 = pk_fma(WZ2[5],  q2.hi, Z2);                                 \
    v2f aZ2 = pk_fma(WZ2[9],  q4.hi, Z2);                                 \
    aZ0 = pk_fma(WZ2[1],  q0.hi, aZ0);                                    \
    aZ1 = pk_fma(WZ2[6],  q3.lo, aZ1);                                    \
    aZ2 = pk_fma(WZ2[10], q5.lo, aZ2);                                    \
    aZ0 = pk_fma(WZ2[2],  q1.lo, aZ0);                                    \
    aZ1 = pk_fma(WZ2[7],  q3.hi, aZ1);                                    \
    aZ2 = pk_fma(WZ2[11], q5.hi, aZ2);                                    \
    aZ0 = pk_fma(WZ2[3],  q1.hi, aZ0);                                    \
    aZ1 = pk_fma(WZ2[8],  q4.lo, aZ1);                                    \
    aZ2 = pk_fma(WZ2[12], q6,    aZ2);                                    \
    aZ0 = pk_fma(WZ2[4],  q2.lo, aZ0);                                    \
    /* Nx: 2 chains 4+4 */                                                \
    v2f aX0 = pk_fma(WNX2[0], q0.lo, BX);                                 \
    v2f aX1 = pk_fma(WNX2[4], q2.lo, Z2);                                 \
    aX0 = pk_fma(WNX2[1], q0.hi, aX0);                                    \
    aX1 = pk_fma(WNX2[5], q2.hi, aX1);                                    \
    aX0 = pk_fma(WNX2[2], q1.lo, aX0);                                    \
    aX1 = pk_fma(WNX2[6], q3.lo, aX1);                                    \
    aX0 = pk_fma(WNX2[3], q1.hi, aX0);                                    \
    aX1 = pk_fma(WNX2[7], q3.hi, aX1);                                    \
    /* Nh: 2 chains 5+4 (WNH2[j] = pair j+4) */                           \
    v2f aH0 = pk_fma(WNH2[0], q2.lo, BH);                                 \
    v2f aH1 = pk_fma(WNH2[5], q4.hi, Z2);                                 \
    aH0 = pk_fma(WNH2[1], q2.hi, aH0);                                    \
    aH1 = pk_fma(WNH2[6], q5.lo, aH1);                                    \
    aH0 = pk_fma(WNH2[2], q3.lo, aH0);                                    \
    aH1 = pk_fma(WNH2[7], q5.hi, aH1);                                    \
    aH0 = pk_fma(WNH2[3], q3.hi, aH0);                                    \
    aH1 = pk_fma(WNH2[8], q6,    aH1);                                    \
    aH0 = pk_fma(WNH2[4], q4.lo, aH0);                                    \
    const float sR  = ((aR0.x + aR0.y) + (aR1.x + aR1.y)) + (aR2.x + aR2.y); \
    const float sZ  = ((aZ0.x + aZ0.y) + (aZ1.x + aZ1.y)) + (aZ2.x + aZ2.y); \
    const float sNx = (aX0.x + aX0.y) + (aX1.x + aX1.y);                  \
    const float sNh = (aH0.x + aH0.y) + (aH1.x + aH1.y);                  \
    const float r = sigm_p(sR);                                           \
    const float z = sigm_p(sZ);                                           \
    const float n = tanh_p(sNx + r * sNh);                                \
    const float hnew = n + z * (h - n);                                   \
    if (HGUARD) h = ((I) >= istart) ? hnew : h;                           \
    else        h = hnew;                                                 \
    *pub = is_x ? (XR) : h;          /* publish h (units) or x(I+1) */    \
    READ_ISSUE();                    /* issue body I+1's window reads */  \
    if (DOSTORE) {                                                        \
      if (is_o)                                                           \
        *(float*)((char*)out + ovoff) = h;   /* t = I-2, exec-masked */   \
      ovoff += OSTEPB;                                                    \
    }                                                                     \
    XR = *(const float*)((const char*)x + xvoff); /* row min(I+7,TT-1) */ \
    if (DOADV) xvoff += XSTEPB;                                           \
    __builtin_amdgcn_wave_barrier(); /* pin body boundary */              \
  }

  // Prologue: I = 0..5 (static guards; all advance xvoff).
  GRU_STEP(0, xr0, true,  false, true)
  GRU_STEP(1, xr1, true,  false, true)
  GRU_STEP(2, xr2, false, true,  true)
  GRU_STEP(3, xr3, false, true,  true)
  GRU_STEP(4, xr4, false, true,  true)
  GRU_STEP(5, xr5, false, true,  true)

  // Steady + tail: i = 6..1025 in 170 unroll-6 packs (1020 bodies).
  // Stores always on; xvoff advance clamps at row TT-1 (uniform check).
#pragma unroll 1
  for (int i = 6; i < TT + 2; i += 6) {
    GRU_STEP(i + 0, xr0, false, true, (i + 0 + 8 < TT))
    GRU_STEP(i + 1, xr1, false, true, (i + 1 + 8 < TT))
    GRU_STEP(i + 2, xr2, false, true, (i + 2 + 8 < TT))
    GRU_STEP(i + 3, xr3, false, true, (i + 3 + 8 < TT))
    GRU_STEP(i + 4, xr4, false, true, (i + 4 + 8 < TT))
    GRU_STEP(i + 5, xr5, false, true, (i + 5 + 8 < TT))
  }

#undef GRU_STEP
#undef READ_ISSUE
}

extern "C" void kernel_launch(void* const* d_in, const int* in_sizes, int n_in,
                              void* d_out, int out_size, void* d_ws, size_t ws_size,
                              hipStream_t stream) {
  (void)in_sizes; (void)n_in; (void)d_ws; (void)ws_size; (void)out_size;
  const float* x     = (const float*)d_in[0];
  const float* w_ih0 = (const float*)d_in[1];
  const float* w_hh0 = (const float*)d_in[2];
  const float* b_ih0 = (const float*)d_in[3];
  const float* b_hh0 = (const float*)d_in[4];
  const float* w_ih1 = (const float*)d_in[5];
  const float* w_hh1 = (const float*)d_in[6];
  const float* b_ih1 = (const float*)d_in[7];
  const float* b_hh1 = (const float*)d_in[8];
  const float* w_ih2 = (const float*)d_in[9];
  const float* w_hh2 = (const float*)d_in[10];
  const float* b_ih2 = (const float*)d_in[11];
  const float* b_hh2 = (const float*)d_in[12];
  float* out = (float*)d_out;

  gru3_fused<<<NB / 2, 64, 0, stream>>>(
      x, w_ih0, w_hh0, b_ih0, b_hh0,
      w_ih1, w_hh1, b_ih1, b_hh1,
      w_ih2, w_hh2, b_ih2, b_hh2, out);
}

// Round 7
// 489.716 us; speedup vs baseline: 1.4356x; 1.0282x over previous
//
#include <hip/hip_runtime.h>

namespace {

constexpr int TT = 1024;   // timesteps
constexpr int NB = 4096;   // batch
constexpr int H0 = 15, H1 = 10, H2 = 2;

// Pre-scales so activations use v_exp_f32 (exp2) directly:
// sigmoid(v) = 1/(1+exp2(-v*L2E)); tanh(u) = 2/(1+exp2(-u*2*L2E)) - 1.
constexpr float L2E  = 1.44269504088896340736f;
constexpr float L2E2 = 2.88539008177792681472f;

// Staging vector per sample (floats): x[0..4] pad[5..7] h0[8..22] pad[23]
// h1[24..33] pad[34..35] h2[36..37] pad[38..47].  Window starts (16B-aligned):
// L0 -> 0 (x+h0), L1 -> 8 (h0+h1), L2 -> 24 (h1+h2). Window = 26 floats used.
constexpr int SSTRIDE = 48;

typedef float v2f __attribute__((ext_vector_type(2)));
typedef float v4f __attribute__((ext_vector_type(4)));

__device__ __forceinline__ float frcp(float v)  { return __builtin_amdgcn_rcpf(v); }
__device__ __forceinline__ float fexp2(float v) { return __builtin_amdgcn_exp2f(v); }
__device__ __forceinline__ float sigm_p(float v) { return frcp(1.0f + fexp2(-v)); }
__device__ __forceinline__ float tanh_p(float u) {
  return __builtin_fmaf(2.0f, frcp(1.0f + fexp2(-u)), -1.0f);
}

// Guaranteed packed FMA: d = a*b + c on both halves (v_pk_fma_f32).
__device__ __forceinline__ v2f pk_fma(v2f a, v2f b, v2f c) {
  v2f d;
  asm("v_pk_fma_f32 %0, %1, %2, %3" : "=v"(d) : "v"(a), "v"(b), "v"(c));
  return d;
}

}  // namespace

// Grid: 2048 blocks x 64 threads = 2 waves/SIMD (grid-limited). Wave = 2
// samples x 32 lanes. Per sample: lanes 0-14 = L0 units, 15-24 = L1 units,
// 25-26 = L2 units, 27-31 = x-loaders. Layers skewed (iter i: L0(i), L1(i-1),
// L2(i-2)) -> one publish/iteration. Single-wave block: wave-lockstep +
// in-order DS pipe; wave_barrier pins compiler ordering.
//
// This revision: BREAK THE SIMD-MATE LOCKSTEP. The two waves sharing each
// SIMD are blocks dispatched together running byte-identical code -> they
// hit their lgkm wait and serial activation chain at the SAME time, so the
// SIMD idles ~21% every iteration (VALUBusy 78.6% @ 450us). Fixes:
//  1. Phase-stagger: s_sleep((blockIdx&3)*~256cyc) before the main loop --
//     SIMD-mates run ~1/4-iteration out of phase; one wave's stall overlaps
//     the other's MAC burst.
//  2. Split lgkm wait: reads return in-order, so wait lgkmcnt(4) (publish
//     write + q0..q2 done), run the 20 pk_fma touching q0..q2, then
//     lgkmcnt(0) for the rest (each wait fenced per rule #18).
//  3. Packed horizontal sums (v_pk_add_f32 via vector adds).
extern "C" __global__ __launch_bounds__(64)
__attribute__((amdgpu_waves_per_eu(2, 2)))
void gru3_fused(
    const float* __restrict__ x,
    const float* __restrict__ w_ih0, const float* __restrict__ w_hh0,
    const float* __restrict__ b_ih0, const float* __restrict__ b_hh0,
    const float* __restrict__ w_ih1, const float* __restrict__ w_hh1,
    const float* __restrict__ b_ih1, const float* __restrict__ b_hh1,
    const float* __restrict__ w_ih2, const float* __restrict__ w_hh2,
    const float* __restrict__ b_ih2, const float* __restrict__ b_hh2,
    float* __restrict__ out) {
  // 2 samples * 48 + tail pad so L2's window over-read stays in-buffer.
  __shared__ __attribute__((aligned(16))) float stage[112];

  const int tid  = threadIdx.x;
  const int lane = tid & 31;
  const int smp  = tid >> 5;
  const int b    = blockIdx.x * 2 + smp;
  const int sbase = smp * SSTRIDE;

  int cls, u;
  if (lane < 15)      { cls = 0; u = lane; }
  else if (lane < 25) { cls = 1; u = lane - 15; }
  else if (lane < 27) { cls = 2; u = lane - 25; }
  else                { cls = 3; u = lane - 27; }   // x-loader

  const int  woff   = (cls == 0) ? 0 : (cls == 1) ? 8 : (cls == 2) ? 24 : 0;
  const int  wpos   = (cls == 0) ? 8 + u : (cls == 1) ? 24 + u
                    : (cls == 2) ? 36 + u : u;
  const int  istart = cls;            // suppress h-update until layer's first step
  const bool is_x   = (cls == 3);
  const bool is_o   = (cls == 2);
  const int  xj     = is_x ? u : 0;   // in-bounds x column for everyone

  // ---- per-lane padded weight vectors (zero outside class's inputs) ----
  float Wr[28], Wz[28], Wnx[28], Wnh[28];
#pragma unroll
  for (int j = 0; j < 28; ++j) { Wr[j] = 0.f; Wz[j] = 0.f; Wnx[j] = 0.f; Wnh[j] = 0.f; }
  float br = 0.f, bz = 0.f, bnx = 0.f, bnh = 0.f;

  if (cls == 0) {
#pragma unroll
    for (int j = 0; j < 5; ++j) {
      Wr [j] = w_ih0[(u         ) * 5 + j] * L2E;
      Wz [j] = w_ih0[(H0 + u    ) * 5 + j] * L2E;
      Wnx[j] = w_ih0[(2 * H0 + u) * 5 + j] * L2E2;
    }
#pragma unroll
    for (int k = 0; k < 15; ++k) {
      Wr [8 + k] = w_hh0[(u         ) * 15 + k] * L2E;
      Wz [8 + k] = w_hh0[(H0 + u    ) * 15 + k] * L2E;
      Wnh[8 + k] = w_hh0[(2 * H0 + u) * 15 + k] * L2E2;
    }
    br  = (b_ih0[u] + b_hh0[u]) * L2E;
    bz  = (b_ih0[H0 + u] + b_hh0[H0 + u]) * L2E;
    bnx = b_ih0[2 * H0 + u] * L2E2;
    bnh = b_hh0[2 * H0 + u] * L2E2;
  } else if (cls == 1) {
#pragma unroll
    for (int k = 0; k < 15; ++k) {
      Wr [k] = w_ih1[(u         ) * 15 + k] * L2E;
      Wz [k] = w_ih1[(H1 + u    ) * 15 + k] * L2E;
      Wnx[k] = w_ih1[(2 * H1 + u) * 15 + k] * L2E2;
    }
#pragma unroll
    for (int k = 0; k < 10; ++k) {
      Wr [16 + k] = w_hh1[(u         ) * 10 + k] * L2E;
      Wz [16 + k] = w_hh1[(H1 + u    ) * 10 + k] * L2E;
      Wnh[16 + k] = w_hh1[(2 * H1 + u) * 10 + k] * L2E2;
    }
    br  = (b_ih1[u] + b_hh1[u]) * L2E;
    bz  = (b_ih1[H1 + u] + b_hh1[H1 + u]) * L2E;
    bnx = b_ih1[2 * H1 + u] * L2E2;
    bnh = b_hh1[2 * H1 + u] * L2E2;
  } else if (cls == 2) {
#pragma unroll
    for (int k = 0; k < 10; ++k) {
      Wr [k] = w_ih2[(u         ) * 10 + k] * L2E;
      Wz [k] = w_ih2[(H2 + u    ) * 10 + k] * L2E;
      Wnx[k] = w_ih2[(2 * H2 + u) * 10 + k] * L2E2;
    }
#pragma unroll
    for (int k = 0; k < 2; ++k) {
      Wr [12 + k] = w_hh2[(u         ) * 2 + k] * L2E;
      Wz [12 + k] = w_hh2[(H2 + u    ) * 2 + k] * L2E;
      Wnh[12 + k] = w_hh2[(2 * H2 + u) * 2 + k] * L2E2;
    }
    br  = (b_ih2[u] + b_hh2[u]) * L2E;
    bz  = (b_ih2[H2 + u] + b_hh2[H2 + u]) * L2E;
    bnx = b_ih2[2 * H2 + u] * L2E2;
    bnh = b_hh2[2 * H2 + u] * L2E2;
  }

  // Pack ONLY the pairs that are nonzero for at least one lane class:
  //   R: pairs 0..12   Z: pairs 0..12   Nx: pairs 0..7   Nh: pairs 4..12
  v2f WR2[13], WZ2[13], WNX2[8], WNH2[9];
#pragma unroll
  for (int j = 0; j < 13; ++j) {
    WR2[j] = (v2f){Wr[2 * j], Wr[2 * j + 1]};
    WZ2[j] = (v2f){Wz[2 * j], Wz[2 * j + 1]};
  }
#pragma unroll
  for (int j = 0; j < 8; ++j)  WNX2[j] = (v2f){Wnx[2 * j], Wnx[2 * j + 1]};
#pragma unroll
  for (int j = 0; j < 9; ++j)  WNH2[j] = (v2f){Wnh[2 * (j + 4)], Wnh[2 * (j + 4) + 1]};

  // Persistent bias pairs (C operand of each chain's first pk_fma -> no movs)
  const v2f BR = (v2f){br,  0.f};
  const v2f BZ = (v2f){bz,  0.f};
  const v2f BX = (v2f){bnx, 0.f};
  const v2f BH = (v2f){bnh, 0.f};
  const v2f Z2 = (v2f){0.f, 0.f};

  // ---- init staging (zeros = h(-1) states + pads), publish x(0) ----
  for (int j = tid; j < 112; j += 64) stage[j] = 0.0f;

  // 6-deep rotating x pipeline: at top of body I, xr{I%6} holds x(I+1)
  // (loaded 6 bodies ago); after publishing it, the same register receives
  // the load of row min(I+7, TT-1). 6 loads stay in flight.
  float xr0, xr1, xr2, xr3, xr4, xr5;
  const size_t xstep = (size_t)NB * 5;
  {
    const size_t base = (size_t)b * 5 + xj;
    const float x0 = x[base];                 // t=0
    xr0 = x[1 * xstep + base];
    xr1 = x[2 * xstep + base];
    xr2 = x[3 * xstep + base];
    xr3 = x[4 * xstep + base];
    xr4 = x[5 * xstep + base];
    xr5 = x[6 * xstep + base];
    if (is_x) stage[sbase + u] = x0;
  }

  float h = 0.0f;
  // LDS byte address of this lane's window (asm ds_read operand).
  const unsigned int wa =
      (unsigned int)(uintptr_t)(&stage[sbase + woff]);
  float* pub = &stage[sbase + wpos];

  // Scalar-base + u32-voffset addressing (1 VALU advance per step):
  //   x row min(I+7,TT-1):  addr = x + xvoff,  xvoff += NB*5*4
  //   out t=I-2:            addr = out + ovoff, ovoff += NB*H2*4
  unsigned int xvoff = (unsigned int)(((size_t)7 * xstep + (size_t)b * 5 + xj) * 4);
  unsigned int ovoff = (unsigned int)(((size_t)b * H2 + (is_o ? u : 0)) * 4);
  constexpr unsigned int XSTEPB = (unsigned int)(NB * 5 * 4);
  constexpr unsigned int OSTEPB = (unsigned int)(NB * H2 * 4);

  // Phase-stagger SIMD-mate blocks (adjacent IDs) by ~0/256/512/768 cycles
  // so their per-iteration stalls (lgkm wait + activation chain) interleave
  // with each other's MAC bursts instead of coinciding. Uniform scalar loop.
  for (int d = (int)(blockIdx.x & 3); d > 0; --d)
    __builtin_amdgcn_s_sleep(4);    // ~4*64 = 256 cycles each

  // Window registers: loop-carried. Written by READ_ISSUE at the END of
  // body I (after that body's publish), consumed by body I+1's MAC block.
  v4f q0, q1, q2, q3, q4, q5; v2f q6;

// Issue the 7 window reads for the NEXT body. Leading wave_barrier pins the
// issue after the preceding publish ds_write (in-order DS pipe then
// guarantees the reads see the freshly published values).
#define READ_ISSUE()                                                      \
    __builtin_amdgcn_wave_barrier();                                      \
    asm volatile(                                                         \
        "ds_read_b128 %0, %7 offset:0\n\t"                                \
        "ds_read_b128 %1, %7 offset:16\n\t"                               \
        "ds_read_b128 %2, %7 offset:32\n\t"                               \
        "ds_read_b128 %3, %7 offset:48\n\t"                               \
        "ds_read_b128 %4, %7 offset:64\n\t"                               \
        "ds_read_b128 %5, %7 offset:80\n\t"                               \
        "ds_read_b64  %6, %7 offset:96"                                   \
        : "=&v"(q0), "=&v"(q1), "=&v"(q2), "=&v"(q3), "=&v"(q4),          \
          "=&v"(q5), "=&v"(q6)                                            \
        : "v"(wa));

  // Prologue read-issue for body 0 (staging holds x(0) + zero states).
  __builtin_amdgcn_wave_barrier();
  READ_ISSUE();

// One skewed-pipeline GRU step.
//   I       : step index (compile-time in prologue, i+k in the loop)
//   XR      : rotating x register (holds x(I+1); reloaded with row I+7)
//   HGUARD  : true only for I=0,1 (istart suppression needed)
//   DOSTORE : I>=2 (store t=I-2 and advance ovoff)
//   DOADV   : advance xvoff iff I+8 < TT (clamps trailing loads to row TT-1)
// Top: partial wait lgkmcnt(4) (in-order DS returns => publish-write and
// q0..q2 complete), region-A MACs touching q0..q2 only; then lgkmcnt(0),
// region-B MACs. Each wait fenced with sched_barrier(0) (rule #18).
// End: publish, then immediately issue next body's reads.
// Pair->window map: P0=q0.lo P1=q0.hi P2=q1.lo P3=q1.hi P4=q2.lo P5=q2.hi
// P6=q3.lo P7=q3.hi P8=q4.lo P9=q4.hi P10=q5.lo P11=q5.hi P12=q6.
#define GRU_STEP(I, XR, HGUARD, DOSTORE, DOADV)                           \
  {                                                                       \
    asm volatile("s_waitcnt lgkmcnt(4)" ::: "memory");                    \
    __builtin_amdgcn_sched_barrier(0);                                    \
    /* ---- region A: q0..q2 chains (20 pk_fma) ---- */                   \
    v2f aR0 = pk_fma(WR2[0],  q0.lo, BR);                                 \
    v2f aZ0 = pk_fma(WZ2[0],  q0.lo, BZ);                                 \
    v2f aX0 = pk_fma(WNX2[0], q0.lo, BX);                                 \
    v2f aH0 = pk_fma(WNH2[0], q2.lo, BH);                                 \
    v2f aR1 = pk_fma(WR2[5],  q2.hi, Z2);                                 \
    v2f aZ1 = pk_fma(WZ2[5],  q2.hi, Z2);                                 \
    v2f aX1 = pk_fma(WNX2[4], q2.lo, Z2);                                 \
    aR0 = pk_fma(WR2[1],  q0.hi, aR0);                                    \
    aZ0 = pk_fma(WZ2[1],  q0.hi, aZ0);                                    \
    aX0 = pk_fma(WNX2[1], q0.hi, aX0);                                    \
    aH0 = pk_fma(WNH2[1], q2.hi, aH0);                                    \
    aX1 = pk_fma(WNX2[5], q2.hi, aX1);                                    \
    aR0 = pk_fma(WR2[2],  q1.lo, aR0);                                    \
    aZ0 = pk_fma(WZ2[2],  q1.lo, aZ0);                                    \
    aX0 = pk_fma(WNX2[2], q1.lo, aX0);                                    \
    aR0 = pk_fma(WR2[3],  q1.hi, aR0);                                    \
    aZ0 = pk_fma(WZ2[3],  q1.hi, aZ0);                                    \
    aX0 = pk_fma(WNX2[3], q1.hi, aX0);                                    \
    aR0 = pk_fma(WR2[4],  q2.lo, aR0);                                    \
    aZ0 = pk_fma(WZ2[4],  q2.lo, aZ0);                                    \
    /* ---- region B: q3..q6 chains (23 pk_fma) ---- */                   \
    asm volatile("s_waitcnt lgkmcnt(0)" ::: "memory");                    \
    __builtin_amdgcn_sched_barrier(0);                                    \
    aR1 = pk_fma(WR2[6],  q3.lo, aR1);                                    \
    aZ1 = pk_fma(WZ2[6],  q3.lo, aZ1);                                    \
    aX1 = pk_fma(WNX2[6], q3.lo, aX1);                                    \
    aH0 = pk_fma(WNH2[2], q3.lo, aH0);                                    \
    aR1 = pk_fma(WR2[7],  q3.hi, aR1);                                    \
    aZ1 = pk_fma(WZ2[7],  q3.hi, aZ1);                                    \
    aX1 = pk_fma(WNX2[7], q3.hi, aX1);                                    \
    aH0 = pk_fma(WNH2[3], q3.hi, aH0);                                    \
    aR1 = pk_fma(WR2[8],  q4.lo, aR1);                                    \
    aZ1 = pk_fma(WZ2[8],  q4.lo, aZ1);                                    \
    aH0 = pk_fma(WNH2[4], q4.lo, aH0);                                    \
    v2f aR2 = pk_fma(WR2[9],  q4.hi, Z2);                                 \
    v2f aZ2 = pk_fma(WZ2[9],  q4.hi, Z2);                                 \
    v2f aH1 = pk_fma(WNH2[5], q4.hi, Z2);                                 \
    aR2 = pk_fma(WR2[10], q5.lo, aR2);                                    \
    aZ2 = pk_fma(WZ2[10], q5.lo, aZ2);                                    \
    aH1 = pk_fma(WNH2[6], q5.lo, aH1);                                    \
    aR2 = pk_fma(WR2[11], q5.hi, aR2);                                    \
    aZ2 = pk_fma(WZ2[11], q5.hi, aZ2);                                    \
    aH1 = pk_fma(WNH2[7], q5.hi, aH1);                                    \
    aR2 = pk_fma(WR2[12], q6,    aR2);                                    \
    aZ2 = pk_fma(WZ2[12], q6,    aZ2);                                    \
    aH1 = pk_fma(WNH2[8], q6,    aH1);                                    \
    /* packed horizontal sums (v_pk_add_f32), then one scalar add each */ \
    const v2f tR = (aR0 + aR1) + aR2;                                     \
    const v2f tZ = (aZ0 + aZ1) + aZ2;                                     \
    const v2f tX = aX0 + aX1;                                             \
    const v2f tH = aH0 + aH1;                                             \
    const float sR  = tR.x + tR.y;                                        \
    const float sZ  = tZ.x + tZ.y;                                        \
    const float sNx = tX.x + tX.y;                                        \
    const float sNh = tH.x + tH.y;                                        \
    const float r = sigm_p(sR);                                           \
    const float z = sigm_p(sZ);                                           \
    const float n = tanh_p(sNx + r * sNh);                                \
    const float hnew = n + z * (h - n);                                   \
    if (HGUARD) h = ((I) >= istart) ? hnew : h;                           \
    else        h = hnew;                                                 \
    *pub = is_x ? (XR) : h;          /* publish h (units) or x(I+1) */    \
    READ_ISSUE();                    /* issue body I+1's window reads */  \
    if (DOSTORE) {                                                        \
      if (is_o)                                                           \
        *(float*)((char*)out + ovoff) = h;   /* t = I-2, exec-masked */   \
      ovoff += OSTEPB;                                                    \
    }                                                                     \
    XR = *(const float*)((const char*)x + xvoff); /* row min(I+7,TT-1) */ \
    if (DOADV) xvoff += XSTEPB;                                           \
    __builtin_amdgcn_wave_barrier(); /* pin body boundary */              \
  }

  // Prologue: I = 0..5 (static guards; all advance xvoff).
  GRU_STEP(0, xr0, true,  false, true)
  GRU_STEP(1, xr1, true,  false, true)
  GRU_STEP(2, xr2, false, true,  true)
  GRU_STEP(3, xr3, false, true,  true)
  GRU_STEP(4, xr4, false, true,  true)
  GRU_STEP(5, xr5, false, true,  true)

  // Steady + tail: i = 6..1025 in 170 unroll-6 packs (1020 bodies).
  // Stores always on; xvoff advance clamps at row TT-1 (uniform check).
#pragma unroll 1
  for (int i = 6; i < TT + 2; i += 6) {
    GRU_STEP(i + 0, xr0, false, true, (i + 0 + 8 < TT))
    GRU_STEP(i + 1, xr1, false, true, (i + 1 + 8 < TT))
    GRU_STEP(i + 2, xr2, false, true, (i + 2 + 8 < TT))
    GRU_STEP(i + 3, xr3, false, true, (i + 3 + 8 < TT))
    GRU_STEP(i + 4, xr4, false, true, (i + 4 + 8 < TT))
    GRU_STEP(i + 5, xr5, false, true, (i + 5 + 8 < TT))
  }

#undef GRU_STEP
#undef READ_ISSUE
}

extern "C" void kernel_launch(void* const* d_in, const int* in_sizes, int n_in,
                              void* d_out, int out_size, void* d_ws, size_t ws_size,
                              hipStream_t stream) {
  (void)in_sizes; (void)n_in; (void)d_ws; (void)ws_size; (void)out_size;
  const float* x     = (const float*)d_in[0];
  const float* w_ih0 = (const float*)d_in[1];
  const float* w_hh0 = (const float*)d_in[2];
  const float* b_ih0 = (const float*)d_in[3];
  const float* b_hh0 = (const float*)d_in[4];
  const float* w_ih1 = (const float*)d_in[5];
  const float* w_hh1 = (const float*)d_in[6];
  const float* b_ih1 = (const float*)d_in[7];
  const float* b_hh1 = (const float*)d_in[8];
  const float* w_ih2 = (const float*)d_in[9];
  const float* w_hh2 = (const float*)d_in[10];
  const float* b_ih2 = (const float*)d_in[11];
  const float* b_hh2 = (const float*)d_in[12];
  float* out = (float*)d_out;

  gru3_fused<<<NB / 2, 64, 0, stream>>>(
      x, w_ih0, w_hh0, b_ih0, b_hh0,
      w_ih1, w_hh1, b_ih1, b_hh1,
      w_ih2, w_hh2, b_ih2, b_hh2, out);
}